// Round 4
// baseline (258.964 us; speedup 1.0000x reference)
//
#include <hip/hip_runtime.h>
#include <hip/hip_bf16.h>

constexpr int BN = 8, HH = 512, WW = 512;
constexpr int PIX = HH * WW;
constexpr float EPSF = 1e-4f;

__device__ __forceinline__ float b2f(__hip_bfloat16 x) { return __bfloat162float(x); }
__device__ __forceinline__ __hip_bfloat16 f2b(float x) { return __float2bfloat16(x); }
__device__ __forceinline__ unsigned short bfbits(float x) {
    union { __hip_bfloat16 b; unsigned short u; } cv; cv.b = f2b(x); return cv.u;
}
// hardware packed f32->bf16 (RNE), 1 instr instead of ~16
__device__ __forceinline__ unsigned int cvtpk(float lo, float hi) {
    unsigned int r;
    asm("v_cvt_pk_bf16_f32 %0, %1, %2" : "=v"(r) : "v"(lo), "v"(hi));
    return r;
}
// silu via hw rcp (h is bf16-quantized downstream; ~2^-22 rel err invisible)
__device__ __forceinline__ float silu(float a) {
    return a * __builtin_amdgcn_rcpf(1.f + __expf(-a));
}

typedef __attribute__((ext_vector_type(8))) short bf16x8;   // MFMA A/B frag (4 VGPRs)
typedef __attribute__((ext_vector_type(4))) float f32x4;    // MFMA C/D frag

// ---- workspace float offsets (small region) ----
constexpr int OFF_TOT = 0;       // 8*16 per-image channel totals (atomics)
constexpr int OFF_ROW0 = 128;
constexpr int OFF_ROW1 = 256;
constexpr int OFF_COL0 = 384;
constexpr int OFF_COL1 = 512;
constexpr int OFF_COR = 640;     // corners [b][hi][wi][16] -> 640..1151
constexpr int OFF_W1R = 1280;    // w1 A-frags hi(512 bf16)+lo(512 bf16) = 512 floats
constexpr int OFF_WR  = 2048;    // w2 A-frags hi(2560 bf16) + lo(2560 bf16)
constexpr int OFF_EH  = 4608;    // 8*37
constexpr int OFF_CH  = 5120;    // 8*37
// ---- big buffers: only tpl (xg computed on the fly in horiz) ----
constexpr size_t OFF_TPB = 65536;                          // tpl fp32 (4 planes)
constexpr size_t TP_BYTES = (size_t)4 * BN * PIX * 4;      // 33,554,432
constexpr size_t WS_NEEDED = OFF_TPB + TP_BYTES;           // ~33.6 MB (134 MB proven)

// ---------------- prep: zero atomic slots, swizzle w1/w2 into hi/lo A-fragments ----------------
// hi = rn-bf16(w), lo = rn-bf16(w - hi): split keeps the ceil(3sd+0.5) path at ~fp32 accuracy
// (bf16-only weights flip the discontinuity -> pi-flips in Hf).
__global__ void prep_kernel(const float* __restrict__ w1, const float* __restrict__ w2,
                            float* __restrict__ wsf) {
    int t = threadIdx.x;
    for (int i = t; i < 640; i += 256) wsf[i] = 0.f;
    // w2 A-frags (conv2): A[oc][k], k = (tap_local)*16 + ic within each K=32 chunk ks
    unsigned short* ab = (unsigned short*)(wsf + OFF_WR);
    for (int idx = t; idx < 5120; idx += 256) {
        int part = idx / 2560;               // 0 = hi, 1 = lo
        int id = idx - part * 2560;
        int ks = id >> 9, rem = id & 511, lane = rem >> 3, j = id & 7;
        int oc = lane & 15, q = lane >> 4;
        int k = q * 8 + j;
        int tap = 2 * ks + (k >> 4), ic = k & 15;
        float val = (tap <= 8) ? w2[oc * 144 + ic * 9 + tap] : 0.f;
        float hv = b2f(f2b(val));
        ab[idx] = (part == 0) ? bfbits(val) : bfbits(val - hv);
    }
    // w1 A-frags (conv1): A[oc][k], k = ic*9 + kh*3 + kw (0..26), pad to 32 with zeros
    unsigned short* a1 = (unsigned short*)(wsf + OFF_W1R);
    for (int idx = t; idx < 1024; idx += 256) {
        int part = idx >> 9;                 // 0 = hi, 1 = lo
        int id = idx & 511;
        int lane = id >> 3, j = id & 7;
        int oc = lane & 15, q = lane >> 4;
        int k = q * 8 + j;
        float val = (k < 27) ? w1[oc * 27 + k] : 0.f;
        float hv = b2f(f2b(val));
        a1[idx] = (part == 0) ? bfbits(val) : bfbits(val - hv);
    }
}

// ---------------- fused conv1(MFMA)+conv2(MFMA)+RGB with conv3-mean reduction ----------------
// Round-4: wave-uniform row-based staging (scalar addressing, interior fast path),
// row-major conv1 groups (no per-iter division, lane-constant swizzle).
// CRITICAL: h1 pixels OUTSIDE the image must be exactly 0 (conv2's zero padding);
// padded-K B values masked to 0 (A=0 there, but NaN*0=NaN in MFMA).
__global__ __launch_bounds__(256) void conv12_kernel(const float* __restrict__ batch,
                                                     const unsigned short* __restrict__ w1buf,
                                                     const float* __restrict__ b1,
                                                     const unsigned short* __restrict__ abuf,
                                                     const float* __restrict__ b2v,
                                                     float* __restrict__ wsf,
                                                     float* __restrict__ out) {
    __shared__ float st[3][12][68];        // batch halo: rows h0-2..h0+9, cols w0-2..w0+65
    __shared__ uint4 h1s[10 * 66 * 2];
    __shared__ float part[4][16];

    int tx = threadIdx.x;
    int lane = tx & 63, wave = tx >> 6;
    int n = lane & 15, q = lane >> 4;
    int w0 = blockIdx.x * 64, h0 = blockIdx.y * 8, b = blockIdx.z;
    bool edgeB = (blockIdx.x == 0) || (blockIdx.x == 7) || (blockIdx.y == 0) || (blockIdx.y == 63);

    union { uint4 u; bf16x8 v; } cv;
    const float* pb = batch + (size_t)(b * 3) * PIX;

    // ---- stage batch halo tile into LDS: 36 (ch,row) pairs x 68 cols, wave-uniform rows ----
    for (int rr = wave; rr < 36; rr += 4) {
        int ch = rr / 12, r = rr - ch * 12;          // wave-uniform
        int gh = h0 - 2 + r;
        const float* rp = pb + (size_t)ch * PIX + (size_t)gh * WW + (w0 - 2);
        if (!edgeB) {
            st[ch][r][lane] = rp[lane];
            if (lane < 4) st[ch][r][64 + lane] = rp[64 + lane];
        } else {
            bool rok = (gh >= 0) && (gh < HH);
            int gw = w0 - 2 + lane;
            float v = (rok && gw >= 0 && gw < WW) ? rp[lane] : 0.f;
            st[ch][r][lane] = v;
            if (lane < 4) {
                int gw2 = gw + 64;
                float v2 = (rok && gw2 >= 0 && gw2 < WW) ? rp[64 + lane] : 0.f;
                st[ch][r][64 + lane] = v2;
            }
        }
    }

    // per-lane conv1 constants
    bf16x8 w1h, w1l;
    const uint4* w14 = (const uint4*)w1buf;
    cv.u = w14[lane];      w1h = cv.v;
    cv.u = w14[64 + lane]; w1l = cv.v;
    int koff[8];
#pragma unroll
    for (int j = 0; j < 8; j++) {
        int k = q * 8 + j;
        int kk = (k < 27) ? k : 0;
        int ic = kk / 9, rem = kk - ic * 9, kh = rem / 3, kw = rem - kh * 3;
        koff[j] = ic * 816 + kh * 68 + kw;
    }
    float b1q[4];
#pragma unroll
    for (int r = 0; r < 4; r++) b1q[r] = b1[q * 4 + r];
    bool hiq = (q == 3);
    int swzl = (n >> 2) & 1;
    __syncthreads();

    // ---- conv1 via MFMA: 10 rows x 5 subs of 16 cols (50 groups) ----
    const float* stf = &st[0][0][0];
    unsigned int* hw = (unsigned int*)h1s;
    for (int g = wave; g < 50; g += 4) {
        int row = g / 5, sub = g - row * 5;          // wave-uniform
        int c = sub * 16 + n;                        // 0..79; valid < 66
        int cc_ = (c < 66) ? c : 65;
        int base = row * 68 + cc_;
        float x[8];
#pragma unroll
        for (int j = 0; j < 8; j++) x[j] = stf[base + koff[j]];
#pragma unroll
        for (int j = 3; j < 8; j++) x[j] = hiq ? 0.f : x[j];   // k>=27 -> finite 0
        union { unsigned int w[4]; bf16x8 v; } bb;
        bb.w[0] = cvtpk(x[0], x[1]);
        bb.w[1] = cvtpk(x[2], x[3]);
        bb.w[2] = cvtpk(x[4], x[5]);
        bb.w[3] = cvtpk(x[6], x[7]);
        f32x4 a = {0, 0, 0, 0};
        a = __builtin_amdgcn_mfma_f32_16x16x32_bf16(w1h, bb.v, a, 0, 0, 0);
        a = __builtin_amdgcn_mfma_f32_16x16x32_bf16(w1l, bb.v, a, 0, 0, 0);
        unsigned int p0 = cvtpk(silu(a[0] + b1q[0]), silu(a[1] + b1q[1]));
        unsigned int p1 = cvtpk(silu(a[2] + b1q[2]), silu(a[3] + b1q[3]));
        if (edgeB) {
            int gh = h0 - 1 + row, gw = w0 - 1 + cc_;
            bool ok = (gh >= 0) && (gh < HH) && (gw >= 0) && (gw < WW);
            p0 = ok ? p0 : 0u;                       // conv2 zero padding
            p1 = ok ? p1 : 0u;
        }
        if (c < 66) {
            int slot = (row * 66 + c) * 2 + ((q >= 2) ? (swzl ^ 1) : swzl);
            *(uint2*)&hw[slot * 4 + (q & 1) * 2] = make_uint2(p0, p1);
        }
    }

    // ---- RGB order channels, inputs from staged fp32 LDS (exact compares) ----
    for (int j = tx; j < 512; j += 256) {
        int rr = j >> 6, ccx = j & 63;
        float v0 = st[0][rr + 2][ccx + 2];
        float v1 = st[1][rr + 2][ccx + 2];
        float v2 = st[2][rr + 2][ccx + 2];
        int mx  = (v0 >= v1 && v0 >= v2) ? 0 : ((v1 >= v2) ? 1 : 2);
        int mx2 = (v2 >= v1 && v2 >= v0) ? 2 : ((v1 >= v0) ? 1 : 0);
        int mn  = (v0 <= v1 && v0 <= v2) ? 0 : ((v1 <= v2) ? 1 : 2);
        int mn2 = (v2 <= v1 && v2 <= v0) ? 2 : ((v1 <= v0) ? 1 : 0);
        size_t p = (size_t)(h0 + rr) * WW + (w0 + ccx);
#pragma unroll
        for (int c = 0; c < 3; c++) {
            float r = 0.5f * ((float)(c == mx) + (float)(c == mx2))
                    - 0.5f * ((float)(c == mn) + (float)(c == mn2));
            out[(size_t)(b * 6 + 2 + c) * PIX + p] = r;
        }
    }
    __syncthreads();

    // ---- conv2 via MFMA + silu + conv3-mean reductions ----
    bf16x8 ah[5], al[5];
    const uint4* ab4 = (const uint4*)abuf;
#pragma unroll
    for (int ks = 0; ks < 5; ks++) {
        cv.u = ab4[ks * 64 + lane];       ah[ks] = cv.v;
        cv.u = ab4[320 + ks * 64 + lane]; al[ks] = cv.v;
    }
    float b2q[4];
#pragma unroll
    for (int r = 0; r < 4; r++) b2q[r] = b2v[q * 4 + r];

    float tt[4] = {0, 0, 0, 0};
    float cs0[4] = {0, 0, 0, 0};
    float cs1[4] = {0, 0, 0, 0};
    for (int rloc = 0; rloc < 2; rloc++) {
        int row = wave * 2 + rloc;
        int grow = h0 + row;
        f32x4 acc[4] = {{0,0,0,0},{0,0,0,0},{0,0,0,0},{0,0,0,0}};
#pragma unroll
        for (int ks = 0; ks < 5; ks++) {
            int tap = 2 * ks + (q >> 1); if (tap > 8) tap = 8;
            int dh = tap / 3 - 1, dw = tap % 3 - 1;
            int half = q & 1;
            int lr = row + 1 + dh;
#pragma unroll
            for (int t = 0; t < 4; t++) {
                int c = 1 + dw + t * 16 + n;
                cv.u = h1s[(lr * 66 + c) * 2 + (half ^ ((c >> 2) & 1))];
                acc[t] = __builtin_amdgcn_mfma_f32_16x16x32_bf16(ah[ks], cv.v, acc[t], 0, 0, 0);
                acc[t] = __builtin_amdgcn_mfma_f32_16x16x32_bf16(al[ks], cv.v, acc[t], 0, 0, 0);
            }
        }
        float sv[4][4];
#pragma unroll
        for (int t = 0; t < 4; t++)
#pragma unroll
            for (int r = 0; r < 4; r++)
                sv[t][r] = silu(acc[t][r] + b2q[r]);
#pragma unroll
        for (int r = 0; r < 4; r++) tt[r] += sv[0][r] + sv[1][r] + sv[2][r] + sv[3][r];
        if (grow == 0 || grow == HH - 1) {
            int off = (grow == 0) ? OFF_ROW0 : OFF_ROW1;
#pragma unroll
            for (int r = 0; r < 4; r++) {
                float x = sv[0][r] + sv[1][r] + sv[2][r] + sv[3][r];
#pragma unroll
                for (int d = 1; d < 16; d <<= 1) x += __shfl_xor(x, d, 64);
                if (n == 0) atomicAdd(&wsf[off + b * 16 + q * 4 + r], x);
            }
        }
        if (blockIdx.x == 0 && n == 0)
#pragma unroll
            for (int r = 0; r < 4; r++) cs0[r] += sv[0][r];
        if (blockIdx.x == 7 && n == 15)
#pragma unroll
            for (int r = 0; r < 4; r++) cs1[r] += sv[3][r];
        if ((grow == 0 || grow == HH - 1)) {
            int hi = (grow == 0) ? 0 : 1;
            if (blockIdx.x == 0 && n == 0)
#pragma unroll
                for (int r = 0; r < 4; r++)
                    wsf[OFF_COR + ((b * 2 + hi) * 2 + 0) * 16 + q * 4 + r] = sv[0][r];
            if (blockIdx.x == 7 && n == 15)
#pragma unroll
                for (int r = 0; r < 4; r++)
                    wsf[OFF_COR + ((b * 2 + hi) * 2 + 1) * 16 + q * 4 + r] = sv[3][r];
        }
    }
    if (blockIdx.x == 0 && n == 0)
#pragma unroll
        for (int r = 0; r < 4; r++) atomicAdd(&wsf[OFF_COL0 + b * 16 + q * 4 + r], cs0[r]);
    if (blockIdx.x == 7 && n == 15)
#pragma unroll
        for (int r = 0; r < 4; r++) atomicAdd(&wsf[OFF_COL1 + b * 16 + q * 4 + r], cs1[r]);
#pragma unroll
    for (int r = 0; r < 4; r++) {
        float x = tt[r];
#pragma unroll
        for (int d = 1; d < 16; d <<= 1) x += __shfl_xor(x, d, 64);
        tt[r] = x;
    }
    if (n == 0)
#pragma unroll
        for (int r = 0; r < 4; r++) part[wave][q * 4 + r] = tt[r];
    __syncthreads();
    if (tx < 16)
        atomicAdd(&wsf[OFF_TOT + b * 16 + tx],
                  part[0][tx] + part[1][tx] + part[2][tx] + part[3][tx]);
}

// ---------------- filter: assemble mean via edge algebra, build separable taps ----------------
__global__ void filter_kernel(const float* __restrict__ w3, const float* __restrict__ b3,
                              float* __restrict__ wsf) {
    int b = blockIdx.x, t = threadIdx.x;   // 160 threads
    __shared__ float red[160];
    float val = 0.f;
    if (t < 144) {
        int ic = t / 9, tap = t % 9, kh = tap / 3, kw = tap % 3;
        float T = wsf[OFF_TOT + b * 16 + ic];
        int hi = -1, wi = -1;
        if (kh == 0) { T -= wsf[OFF_ROW1 + b * 16 + ic]; hi = 1; }
        else if (kh == 2) { T -= wsf[OFF_ROW0 + b * 16 + ic]; hi = 0; }
        if (kw == 0) { T -= wsf[OFF_COL1 + b * 16 + ic]; wi = 1; }
        else if (kw == 2) { T -= wsf[OFF_COL0 + b * 16 + ic]; wi = 0; }
        if (hi >= 0 && wi >= 0) T += wsf[OFF_COR + ((b * 2 + hi) * 2 + wi) * 16 + ic];
        val = w3[t] * T;
    }
    red[t] = val;
    __syncthreads();
    __shared__ float sh_mean;
    if (t == 0) {
        float S = 0.f;
        for (int i = 0; i < 144; i++) S += red[i];
        sh_mean = b3[0] + S * (1.f / (float)PIX);
    }
    __syncthreads();
    float scale = fminf(2.5f, fmaxf(-2.5f, sh_mean));
    float sd = exp2f(scale);
    float fs = ceilf(3.f * sd + 0.5f);
    float e = 0.f, c = 0.f;
    if (t < 37) {
        float x = (float)(t - 18);
        if (fabsf(x) <= fs) {
            float qq = x / sd;
            e = __expf(-0.5f * qq * qq);
            c = -x / (sd * sd * sd * 6.28318530717958647692f) * e;
        }
    }
    __shared__ float sa[40], sb[40];
    if (t < 37) { sa[t] = e; sb[t] = fabsf(c); }
    __syncthreads();
    __shared__ float Se, Sc;
    if (t == 0) {
        float a = 0.f, d = 0.f;
        for (int i = 0; i < 37; i++) { a += sa[i]; d += sb[i]; }
        Se = a; Sc = d;
    }
    __syncthreads();
    if (t < 37) {
        wsf[OFF_EH + b * 37 + t] = e / Se;
        wsf[OFF_CH + b * 37 + t] = c / Sc;
    }
}

// ---------------- horizontal pass: batch -> xg (on the fly) -> t0..t3 ----------------
// Round-4: coefficients staged in LDS; 40-tap loop split prologue(3)/main(34, guard-
// free, sliding coefficient window)/epilogue(3).
__device__ __forceinline__ int skw(int c) { return c + (c >> 5); }
__global__ __launch_bounds__(256, 4) void horiz_kernel(const float* __restrict__ batch,
                                                       const float* __restrict__ gcm,
                                                       const float* __restrict__ ehat,
                                                       const float* __restrict__ chat,
                                                       float* __restrict__ t) {
    __shared__ float xr[2][3][566];        // skewed: logical col 0..547 -> skw(c)
    __shared__ float cE[40], cC[40];
    int tx = threadIdx.x;
    int h0 = blockIdx.x * 2;
    int b  = blockIdx.y;
    if (tx < 37) { cE[tx] = ehat[b * 37 + tx]; cC[tx] = chat[b * 37 + tx]; }
    const float* pb = batch + (size_t)(b * 3) * PIX;
    float g0 = gcm[0], g1 = gcm[1], g2 = gcm[2];
    float g3 = gcm[3], g4 = gcm[4], g5 = gcm[5];
    float g6 = gcm[6], g7 = gcm[7], g8 = gcm[8];
    for (int i = tx; i < 2 * 548; i += 256) {
        int r = i / 548, c = i - r * 548;
        int gw = c - 18;
        float v0 = 0.f, v1 = 0.f, v2 = 0.f;
        if (gw >= 0 && gw < WW) {
            size_t p = (size_t)(h0 + r) * WW + gw;
            v0 = pb[p]; v1 = pb[(size_t)PIX + p]; v2 = pb[2 * (size_t)PIX + p];
        }
        int cs = skw(c);
        xr[r][0][cs] = g0 * v0 + g1 * v1 + g2 * v2;
        xr[r][1][cs] = g3 * v0 + g4 * v1 + g5 * v2;
        xr[r][2][cs] = g6 * v0 + g7 * v1 + g8 * v2;
    }
    __syncthreads();
    int r = tx >> 7, colbase = (tx & 127) * 4;
    float a0[4] = {}, a1[4] = {}, a2[4] = {}, a3[4] = {};
    float e1, e2, e3, d1, d2, d3;
    {   // prologue kk = 0..2 (i <= kk), seeds the coefficient window
        float ce[3], cc2[3];
#pragma unroll
        for (int k = 0; k < 3; k++) { ce[k] = cE[k]; cc2[k] = cC[k]; }
#pragma unroll
        for (int kk = 0; kk < 3; kk++) {
            int cs = skw(colbase + kk);
            float x0 = xr[r][0][cs], x1 = xr[r][1][cs], x2 = xr[r][2][cs];
#pragma unroll
            for (int i = 0; i < 3; i++) {
                if (i <= kk) {
                    float ce_ = ce[kk - i], cc_ = cc2[kk - i];
                    a0[i] += ce_ * x0; a1[i] += ce_ * x1;
                    a2[i] += ce_ * x2; a3[i] += cc_ * x0;
                }
            }
        }
        e1 = ce[2]; e2 = ce[1]; e3 = ce[0];
        d1 = cc2[2]; d2 = cc2[1]; d3 = cc2[0];
    }
#pragma unroll 2
    for (int kk = 3; kk < 37; kk++) {      // main: all 4 outputs valid, no guards
        float e0 = cE[kk], d0 = cC[kk];
        int cs = skw(colbase + kk);
        float x0 = xr[r][0][cs], x1 = xr[r][1][cs], x2 = xr[r][2][cs];
        a0[0] += e0 * x0; a1[0] += e0 * x1; a2[0] += e0 * x2; a3[0] += d0 * x0;
        a0[1] += e1 * x0; a1[1] += e1 * x1; a2[1] += e1 * x2; a3[1] += d1 * x0;
        a0[2] += e2 * x0; a1[2] += e2 * x1; a2[2] += e2 * x2; a3[2] += d2 * x0;
        a0[3] += e3 * x0; a1[3] += e3 * x1; a2[3] += e3 * x2; a3[3] += d3 * x0;
        e3 = e2; e2 = e1; e1 = e0; d3 = d2; d2 = d1; d1 = d0;
    }
    {   // kk = 37 (e1=cE[36], e2=cE[35], e3=cE[34])
        int cs = skw(colbase + 37);
        float x0 = xr[r][0][cs], x1 = xr[r][1][cs], x2 = xr[r][2][cs];
        a0[1] += e1 * x0; a1[1] += e1 * x1; a2[1] += e1 * x2; a3[1] += d1 * x0;
        a0[2] += e2 * x0; a1[2] += e2 * x1; a2[2] += e2 * x2; a3[2] += d2 * x0;
        a0[3] += e3 * x0; a1[3] += e3 * x1; a2[3] += e3 * x2; a3[3] += d3 * x0;
    }
    {   // kk = 38
        int cs = skw(colbase + 38);
        float x0 = xr[r][0][cs], x1 = xr[r][1][cs], x2 = xr[r][2][cs];
        a0[2] += e1 * x0; a1[2] += e1 * x1; a2[2] += e1 * x2; a3[2] += d1 * x0;
        a0[3] += e2 * x0; a1[3] += e2 * x1; a2[3] += e2 * x2; a3[3] += d2 * x0;
    }
    {   // kk = 39
        int cs = skw(colbase + 39);
        float x0 = xr[r][0][cs], x1 = xr[r][1][cs], x2 = xr[r][2][cs];
        a0[3] += e1 * x0; a1[3] += e1 * x1; a2[3] += e1 * x2; a3[3] += d1 * x0;
    }
    const size_t PL = (size_t)BN * PIX;
    size_t p = (size_t)b * PIX + (size_t)(h0 + r) * WW + colbase;
    *(float4*)&t[0 * PL + p] = make_float4(a0[0], a0[1], a0[2], a0[3]);
    *(float4*)&t[1 * PL + p] = make_float4(a1[0], a1[1], a1[2], a1[3]);
    *(float4*)&t[2 * PL + p] = make_float4(a2[0], a2[1], a2[2], a2[3]);
    *(float4*)&t[3 * PL + p] = make_float4(a3[0], a3[1], a3[2], a3[3]);
}

// ---------------- vertical pass + final math -> out ch0,1,5 (4-row sliding/thread) ----------------
// Round-4: LDS coefficients, guard-free main loop with pointer-increment addressing,
// wave-uniform safe-path (30/32 y-blocks never touch the image border).
#define VACC(ee, dd, ii) { E[ii] += (ee) * v0; Ex[ii] += (dd) * v0; Ey[ii] += (ee) * v3; \
                           El[ii] += (ee) * v1; Ell[ii] += (ee) * v2; }
__global__ __launch_bounds__(256, 4) void vert_kernel(const float* __restrict__ t,
                                                      const float* __restrict__ ehat,
                                                      const float* __restrict__ chat,
                                                      float* __restrict__ out) {
    __shared__ float cE[40], cC[40];
    int tx = threadIdx.x;
    int b = blockIdx.z;
    if (tx < 37) { cE[tx] = ehat[b * 37 + tx]; cC[tx] = chat[b * 37 + tx]; }
    int j = blockIdx.x * 64 + (tx & 63);
    int r0 = (blockIdx.y * 4 + (tx >> 6)) * 4;
    const size_t PL = (size_t)BN * PIX;
    const float* t0 = t + (size_t)b * PIX;
    __syncthreads();
    float E[4] = {}, Ex[4] = {}, Ey[4] = {}, El[4] = {}, Ell[4] = {};
    bool safe = (r0 >= 18) && (r0 <= HH - 22);       // all 40 rows in-range (wave-uniform)
    float e1, e2, e3, d1, d2, d3;
    {   // prologue kk = 0..2
        float ce[3], cc2[3];
#pragma unroll
        for (int k = 0; k < 3; k++) { ce[k] = cE[k]; cc2[k] = cC[k]; }
#pragma unroll
        for (int kk = 0; kk < 3; kk++) {
            int gr = r0 - 18 + kk;
            float v0 = 0.f, v1 = 0.f, v2 = 0.f, v3 = 0.f;
            if ((unsigned)gr < (unsigned)HH) {
                size_t idx = (size_t)gr * WW + j;
                v0 = t0[idx]; v1 = t0[PL + idx]; v2 = t0[2 * PL + idx]; v3 = t0[3 * PL + idx];
            }
#pragma unroll
            for (int i = 0; i < 3; i++) {
                if (i <= kk) {
                    float ee = ce[kk - i], dd = cc2[kk - i];
                    VACC(ee, dd, i)
                }
            }
        }
        e1 = ce[2]; e2 = ce[1]; e3 = ce[0];
        d1 = cc2[2]; d2 = cc2[1]; d3 = cc2[0];
    }
    const float* pv = t0 + (size_t)(r0 - 15) * WW + j;   // row at kk=3
    if (safe) {
#pragma unroll 2
        for (int kk = 3; kk < 37; kk++) {
            float e0 = cE[kk], d0 = cC[kk];
            float v0 = pv[0], v1 = pv[PL], v2 = pv[2 * PL], v3 = pv[3 * PL];
            VACC(e0, d0, 0) VACC(e1, d1, 1) VACC(e2, d2, 2) VACC(e3, d3, 3)
            e3 = e2; e2 = e1; e1 = e0; d3 = d2; d2 = d1; d1 = d0;
            pv += WW;
        }
    } else {
        int gr = r0 - 15;
#pragma unroll 2
        for (int kk = 3; kk < 37; kk++) {
            float e0 = cE[kk], d0 = cC[kk];
            float v0 = 0.f, v1 = 0.f, v2 = 0.f, v3 = 0.f;
            if ((unsigned)gr < (unsigned)HH) {
                v0 = pv[0]; v1 = pv[PL]; v2 = pv[2 * PL]; v3 = pv[3 * PL];
            }
            VACC(e0, d0, 0) VACC(e1, d1, 1) VACC(e2, d2, 2) VACC(e3, d3, 3)
            e3 = e2; e2 = e1; e1 = e0; d3 = d2; d2 = d1; d1 = d0;
            pv += WW; gr++;
        }
    }
    // epilogue kk = 37..39 (e1=cE[36], e2=cE[35], e3=cE[34]; no rotation)
#pragma unroll
    for (int kk = 37; kk < 40; kk++) {
        int gr = r0 - 18 + kk;                        // >= 19, may exceed 511
        float v0 = 0.f, v1 = 0.f, v2 = 0.f, v3 = 0.f;
        if (gr < HH) {
            size_t idx = (size_t)gr * WW + j;
            v0 = t0[idx]; v1 = t0[PL + idx]; v2 = t0[2 * PL + idx]; v3 = t0[3 * PL + idx];
        }
        if (kk == 37) { VACC(e1, d1, 1) VACC(e2, d2, 2) VACC(e3, d3, 3) }
        if (kk == 38) { VACC(e1, d1, 2) VACC(e2, d2, 3) }
        if (kk == 39) { VACC(e1, d1, 3) }
    }
#pragma unroll
    for (int i = 0; i < 4; i++) {
        int h = r0 + i;
        float Hf = atanf(El[i] / (Ell[i] + EPSF));
        float S = logf((El[i] * El[i] + Ell[i] * Ell[i]) / (E[i] * E[i] + EPSF) + EPSF);
        float rx = Ex[i] / (E[i] + EPSF), ry = Ey[i] / (E[i] + EPSF);
        float Wv = atanf(rx * rx + ry * ry);
        size_t base = (size_t)(b * 6) * PIX + (size_t)h * WW + j;
        out[base] = Hf;
        out[base + PIX] = S;
        out[base + 5 * (size_t)PIX] = Wv;
    }
}
#undef VACC

extern "C" void kernel_launch(void* const* d_in, const int* in_sizes, int n_in,
                              void* d_out, int out_size, void* d_ws, size_t ws_size,
                              hipStream_t stream) {
    const float* batch = (const float*)d_in[0];
    const float* gcm   = (const float*)d_in[1];
    const float* w1    = (const float*)d_in[2];
    const float* b1    = (const float*)d_in[3];
    const float* w2    = (const float*)d_in[4];
    const float* b2    = (const float*)d_in[5];
    const float* w3    = (const float*)d_in[6];
    const float* b3    = (const float*)d_in[7];
    float* out = (float*)d_out;

    if (ws_size < WS_NEEDED) return;

    float* wsf = (float*)d_ws;
    float* tpl = (float*)((char*)d_ws + OFF_TPB);
    float* ehat = wsf + OFF_EH;
    float* chat = wsf + OFF_CH;

    prep_kernel<<<dim3(1), dim3(256), 0, stream>>>(w1, w2, wsf);
    conv12_kernel<<<dim3(8, 64, 8), dim3(256), 0, stream>>>(
        batch, (const unsigned short*)(wsf + OFF_W1R), b1,
        (const unsigned short*)(wsf + OFF_WR), b2, wsf, out);
    filter_kernel<<<dim3(8), dim3(160), 0, stream>>>(w3, b3, wsf);
    horiz_kernel<<<dim3(256, 8), dim3(256), 0, stream>>>(batch, gcm, ehat, chat, tpl);
    vert_kernel<<<dim3(8, 32, 8), dim3(256), 0, stream>>>(tpl, ehat, chat, out);
}

// Round 5
// 242.989 us; speedup vs baseline: 1.0657x; 1.0657x over previous
//
#include <hip/hip_runtime.h>
#include <hip/hip_bf16.h>

constexpr int BN = 8, HH = 512, WW = 512;
constexpr int PIX = HH * WW;
constexpr float EPSF = 1e-4f;

__device__ __forceinline__ float b2f(__hip_bfloat16 x) { return __bfloat162float(x); }
__device__ __forceinline__ __hip_bfloat16 f2b(float x) { return __float2bfloat16(x); }
__device__ __forceinline__ unsigned short bfbits(float x) {
    union { __hip_bfloat16 b; unsigned short u; } cv; cv.b = f2b(x); return cv.u;
}
// hardware packed f32->bf16 (RNE), 1 instr instead of ~16
__device__ __forceinline__ unsigned int cvtpk(float lo, float hi) {
    unsigned int r;
    asm("v_cvt_pk_bf16_f32 %0, %1, %2" : "=v"(r) : "v"(lo), "v"(hi));
    return r;
}
// silu via hw rcp (h is bf16-quantized downstream; ~2^-22 rel err invisible)
__device__ __forceinline__ float silu(float a) {
    return a * __builtin_amdgcn_rcpf(1.f + __expf(-a));
}

typedef __attribute__((ext_vector_type(8))) short bf16x8;   // MFMA A/B frag (4 VGPRs)
typedef __attribute__((ext_vector_type(4))) float f32x4;    // MFMA C/D frag

// ---- workspace float offsets (small region) ----
constexpr int OFF_TOT = 0;       // 8*16 per-image channel totals (atomics)
constexpr int OFF_ROW0 = 128;
constexpr int OFF_ROW1 = 256;
constexpr int OFF_COL0 = 384;
constexpr int OFF_COL1 = 512;
constexpr int OFF_COR = 640;     // corners [b][hi][wi][16] -> 640..1151
constexpr int OFF_W1R = 1280;    // w1 A-frags hi(512 bf16)+lo(512 bf16) = 512 floats
constexpr int OFF_WR  = 2048;    // w2 A-frags hi(2560 bf16) + lo(2560 bf16)
constexpr int OFF_EH  = 4608;    // 8*37
constexpr int OFF_CH  = 5120;    // 8*37
// ---- big buffers: only tpl (xg computed on the fly in horiz) ----
constexpr size_t OFF_TPB = 65536;                          // tpl fp32 (4 planes)
constexpr size_t TP_BYTES = (size_t)4 * BN * PIX * 4;      // 33,554,432
constexpr size_t WS_NEEDED = OFF_TPB + TP_BYTES;           // ~33.6 MB (134 MB proven)

// ---------------- prep: zero atomic slots, swizzle w1/w2 into hi/lo A-fragments ----------------
// hi = rn-bf16(w), lo = rn-bf16(w - hi): split keeps the ceil(3sd+0.5) path at ~fp32 accuracy
// (bf16-only weights flip the discontinuity -> pi-flips in Hf).
__global__ void prep_kernel(const float* __restrict__ w1, const float* __restrict__ w2,
                            float* __restrict__ wsf) {
    int t = threadIdx.x;
    for (int i = t; i < 640; i += 256) wsf[i] = 0.f;
    // w2 A-frags (conv2): A[oc][k], k = (tap_local)*16 + ic within each K=32 chunk ks
    unsigned short* ab = (unsigned short*)(wsf + OFF_WR);
    for (int idx = t; idx < 5120; idx += 256) {
        int part = idx / 2560;               // 0 = hi, 1 = lo
        int id = idx - part * 2560;
        int ks = id >> 9, rem = id & 511, lane = rem >> 3, j = id & 7;
        int oc = lane & 15, q = lane >> 4;
        int k = q * 8 + j;
        int tap = 2 * ks + (k >> 4), ic = k & 15;
        float val = (tap <= 8) ? w2[oc * 144 + ic * 9 + tap] : 0.f;
        float hv = b2f(f2b(val));
        ab[idx] = (part == 0) ? bfbits(val) : bfbits(val - hv);
    }
    // w1 A-frags (conv1): A[oc][k], k = ic*9 + kh*3 + kw (0..26), pad to 32 with zeros
    unsigned short* a1 = (unsigned short*)(wsf + OFF_W1R);
    for (int idx = t; idx < 1024; idx += 256) {
        int part = idx >> 9;                 // 0 = hi, 1 = lo
        int id = idx & 511;
        int lane = id >> 3, j = id & 7;
        int oc = lane & 15, q = lane >> 4;
        int k = q * 8 + j;
        float val = (k < 27) ? w1[oc * 27 + k] : 0.f;
        float hv = b2f(f2b(val));
        a1[idx] = (part == 0) ? bfbits(val) : bfbits(val - hv);
    }
}

// ---------------- fused conv1(MFMA)+conv2(MFMA)+RGB with conv3-mean reduction ----------------
// Round-5: conv12 reverted to the round-3 form (flat 42-group conv1 = 672 slots;
// round-4's row-major 50-group split was +19% MFMA/gather work -> 111->139us regression).
// CRITICAL: h1 pixels OUTSIDE the image must be exactly 0 (conv2's zero padding);
// padded-K B values masked to 0 (A=0 there, but NaN*0=NaN in MFMA).
__global__ __launch_bounds__(256) void conv12_kernel(const float* __restrict__ batch,
                                                     const unsigned short* __restrict__ w1buf,
                                                     const float* __restrict__ b1,
                                                     const unsigned short* __restrict__ abuf,
                                                     const float* __restrict__ b2v,
                                                     float* __restrict__ wsf,
                                                     float* __restrict__ out) {
    __shared__ float st[3][12][68];        // batch halo: rows h0-2..h0+9, cols w0-2..w0+65
    __shared__ uint4 h1s[10 * 66 * 2];
    __shared__ float part[4][16];

    int tx = threadIdx.x;
    int lane = tx & 63, wave = tx >> 6;
    int n = lane & 15, q = lane >> 4;
    int w0 = blockIdx.x * 64, h0 = blockIdx.y * 8, b = blockIdx.z;

    union { uint4 u; bf16x8 v; } cv;
    const float* pb = batch + (size_t)(b * 3) * PIX;

    // ---- stage batch halo tile into LDS (coalesced, zero-padded) ----
    for (int i = tx; i < 2448; i += 256) {           // 3 ch * 12 rows * 68 cols
        int ch = i / 816;
        int rem = i - ch * 816;
        int r = rem / 68, c = rem - r * 68;
        int gh = h0 - 2 + r, gw = w0 - 2 + c;
        float v = 0.f;
        if (gh >= 0 && gh < HH && gw >= 0 && gw < WW)
            v = pb[(size_t)ch * PIX + (size_t)gh * WW + gw];
        st[ch][r][c] = v;
    }

    // per-lane conv1 constants (independent of groups)
    bf16x8 w1h, w1l;
    const uint4* w14 = (const uint4*)w1buf;
    cv.u = w14[lane];      w1h = cv.v;
    cv.u = w14[64 + lane]; w1l = cv.v;
    int koff[8];
#pragma unroll
    for (int j = 0; j < 8; j++) {
        int k = q * 8 + j;
        int kk = (k < 27) ? k : 0;
        int ic = kk / 9, rem = kk - ic * 9, kh = rem / 3, kw = rem - kh * 3;
        koff[j] = ic * 816 + kh * 68 + kw;
    }
    float b1q[4];
#pragma unroll
    for (int r = 0; r < 4; r++) b1q[r] = b1[q * 4 + r];
    bool hiq = (q == 3);
    __syncthreads();

    // ---- conv1 via MFMA over the 10x66 h1 halo (660 px, 42 groups of 16) ----
    const float* stf = &st[0][0][0];
    unsigned int* hw = (unsigned int*)h1s;
    for (int g = wave; g < 42; g += 4) {
        int i = g * 16 + n; if (i > 659) i = 659;    // clamp: dup writes same data
        int r = i / 66, c = i - r * 66;              // h1 pixel (h0-1+r, w0-1+c)
        int base = r * 68 + c;
        float x[8];
#pragma unroll
        for (int j = 0; j < 8; j++) x[j] = stf[base + koff[j]];
#pragma unroll
        for (int j = 3; j < 8; j++) x[j] = hiq ? 0.f : x[j];   // k>=27 -> finite 0
        union { unsigned int w[4]; bf16x8 v; } bb;
        bb.w[0] = cvtpk(x[0], x[1]);
        bb.w[1] = cvtpk(x[2], x[3]);
        bb.w[2] = cvtpk(x[4], x[5]);
        bb.w[3] = cvtpk(x[6], x[7]);
        f32x4 a = {0, 0, 0, 0};
        a = __builtin_amdgcn_mfma_f32_16x16x32_bf16(w1h, bb.v, a, 0, 0, 0);
        a = __builtin_amdgcn_mfma_f32_16x16x32_bf16(w1l, bb.v, a, 0, 0, 0);
        int gh = h0 - 1 + r, gw = w0 - 1 + c;
        bool ok = ((unsigned)gh < (unsigned)HH) && ((unsigned)gw < (unsigned)WW);
        unsigned int p0 = cvtpk(silu(a[0] + b1q[0]), silu(a[1] + b1q[1]));
        unsigned int p1 = cvtpk(silu(a[2] + b1q[2]), silu(a[3] + b1q[3]));
        p0 = ok ? p0 : 0u;                           // conv2 zero padding
        p1 = ok ? p1 : 0u;
        int swz = (c >> 2) & 1;
        int slot = i * 2 + ((q >= 2) ? (swz ^ 1) : swz);
        *(uint2*)&hw[slot * 4 + (q & 1) * 2] = make_uint2(p0, p1);
    }

    // ---- RGB order channels, inputs from staged fp32 LDS (exact compares) ----
    for (int j = tx; j < 512; j += 256) {
        int rr = j >> 6, ccx = j & 63;
        float v0 = st[0][rr + 2][ccx + 2];
        float v1 = st[1][rr + 2][ccx + 2];
        float v2 = st[2][rr + 2][ccx + 2];
        int mx  = (v0 >= v1 && v0 >= v2) ? 0 : ((v1 >= v2) ? 1 : 2);
        int mx2 = (v2 >= v1 && v2 >= v0) ? 2 : ((v1 >= v0) ? 1 : 0);
        int mn  = (v0 <= v1 && v0 <= v2) ? 0 : ((v1 <= v2) ? 1 : 2);
        int mn2 = (v2 <= v1 && v2 <= v0) ? 2 : ((v1 <= v0) ? 1 : 0);
        size_t p = (size_t)(h0 + rr) * WW + (w0 + ccx);
#pragma unroll
        for (int c = 0; c < 3; c++) {
            float r = 0.5f * ((float)(c == mx) + (float)(c == mx2))
                    - 0.5f * ((float)(c == mn) + (float)(c == mn2));
            out[(size_t)(b * 6 + 2 + c) * PIX + p] = r;
        }
    }
    __syncthreads();

    // ---- conv2 via MFMA + silu + conv3-mean reductions ----
    bf16x8 ah[5], al[5];
    const uint4* ab4 = (const uint4*)abuf;
#pragma unroll
    for (int ks = 0; ks < 5; ks++) {
        cv.u = ab4[ks * 64 + lane];       ah[ks] = cv.v;
        cv.u = ab4[320 + ks * 64 + lane]; al[ks] = cv.v;
    }
    float b2q[4];
#pragma unroll
    for (int r = 0; r < 4; r++) b2q[r] = b2v[q * 4 + r];

    float tt[4] = {0, 0, 0, 0};
    float cs0[4] = {0, 0, 0, 0};
    float cs1[4] = {0, 0, 0, 0};
    for (int rloc = 0; rloc < 2; rloc++) {
        int row = wave * 2 + rloc;
        int grow = h0 + row;
        f32x4 acc[4] = {{0,0,0,0},{0,0,0,0},{0,0,0,0},{0,0,0,0}};
#pragma unroll
        for (int ks = 0; ks < 5; ks++) {
            int tap = 2 * ks + (q >> 1); if (tap > 8) tap = 8;
            int dh = tap / 3 - 1, dw = tap % 3 - 1;
            int half = q & 1;
            int lr = row + 1 + dh;
#pragma unroll
            for (int t = 0; t < 4; t++) {
                int c = 1 + dw + t * 16 + n;
                cv.u = h1s[(lr * 66 + c) * 2 + (half ^ ((c >> 2) & 1))];
                acc[t] = __builtin_amdgcn_mfma_f32_16x16x32_bf16(ah[ks], cv.v, acc[t], 0, 0, 0);
                acc[t] = __builtin_amdgcn_mfma_f32_16x16x32_bf16(al[ks], cv.v, acc[t], 0, 0, 0);
            }
        }
        float sv[4][4];
#pragma unroll
        for (int t = 0; t < 4; t++)
#pragma unroll
            for (int r = 0; r < 4; r++)
                sv[t][r] = silu(acc[t][r] + b2q[r]);
#pragma unroll
        for (int r = 0; r < 4; r++) tt[r] += sv[0][r] + sv[1][r] + sv[2][r] + sv[3][r];
        if (grow == 0 || grow == HH - 1) {
            int off = (grow == 0) ? OFF_ROW0 : OFF_ROW1;
#pragma unroll
            for (int r = 0; r < 4; r++) {
                float x = sv[0][r] + sv[1][r] + sv[2][r] + sv[3][r];
#pragma unroll
                for (int d = 1; d < 16; d <<= 1) x += __shfl_xor(x, d, 64);
                if (n == 0) atomicAdd(&wsf[off + b * 16 + q * 4 + r], x);
            }
        }
        if (blockIdx.x == 0 && n == 0)
#pragma unroll
            for (int r = 0; r < 4; r++) cs0[r] += sv[0][r];
        if (blockIdx.x == 7 && n == 15)
#pragma unroll
            for (int r = 0; r < 4; r++) cs1[r] += sv[3][r];
        if ((grow == 0 || grow == HH - 1)) {
            int hi = (grow == 0) ? 0 : 1;
            if (blockIdx.x == 0 && n == 0)
#pragma unroll
                for (int r = 0; r < 4; r++)
                    wsf[OFF_COR + ((b * 2 + hi) * 2 + 0) * 16 + q * 4 + r] = sv[0][r];
            if (blockIdx.x == 7 && n == 15)
#pragma unroll
                for (int r = 0; r < 4; r++)
                    wsf[OFF_COR + ((b * 2 + hi) * 2 + 1) * 16 + q * 4 + r] = sv[3][r];
        }
    }
    if (blockIdx.x == 0 && n == 0)
#pragma unroll
        for (int r = 0; r < 4; r++) atomicAdd(&wsf[OFF_COL0 + b * 16 + q * 4 + r], cs0[r]);
    if (blockIdx.x == 7 && n == 15)
#pragma unroll
        for (int r = 0; r < 4; r++) atomicAdd(&wsf[OFF_COL1 + b * 16 + q * 4 + r], cs1[r]);
#pragma unroll
    for (int r = 0; r < 4; r++) {
        float x = tt[r];
#pragma unroll
        for (int d = 1; d < 16; d <<= 1) x += __shfl_xor(x, d, 64);
        tt[r] = x;
    }
    if (n == 0)
#pragma unroll
        for (int r = 0; r < 4; r++) part[wave][q * 4 + r] = tt[r];
    __syncthreads();
    if (tx < 16)
        atomicAdd(&wsf[OFF_TOT + b * 16 + tx],
                  part[0][tx] + part[1][tx] + part[2][tx] + part[3][tx]);
}

// ---------------- filter: assemble mean via edge algebra, build separable taps ----------------
__global__ void filter_kernel(const float* __restrict__ w3, const float* __restrict__ b3,
                              float* __restrict__ wsf) {
    int b = blockIdx.x, t = threadIdx.x;   // 160 threads
    __shared__ float red[160];
    float val = 0.f;
    if (t < 144) {
        int ic = t / 9, tap = t % 9, kh = tap / 3, kw = tap % 3;
        float T = wsf[OFF_TOT + b * 16 + ic];
        int hi = -1, wi = -1;
        if (kh == 0) { T -= wsf[OFF_ROW1 + b * 16 + ic]; hi = 1; }
        else if (kh == 2) { T -= wsf[OFF_ROW0 + b * 16 + ic]; hi = 0; }
        if (kw == 0) { T -= wsf[OFF_COL1 + b * 16 + ic]; wi = 1; }
        else if (kw == 2) { T -= wsf[OFF_COL0 + b * 16 + ic]; wi = 0; }
        if (hi >= 0 && wi >= 0) T += wsf[OFF_COR + ((b * 2 + hi) * 2 + wi) * 16 + ic];
        val = w3[t] * T;
    }
    red[t] = val;
    __syncthreads();
    __shared__ float sh_mean;
    if (t == 0) {
        float S = 0.f;
        for (int i = 0; i < 144; i++) S += red[i];
        sh_mean = b3[0] + S * (1.f / (float)PIX);
    }
    __syncthreads();
    float scale = fminf(2.5f, fmaxf(-2.5f, sh_mean));
    float sd = exp2f(scale);
    float fs = ceilf(3.f * sd + 0.5f);
    float e = 0.f, c = 0.f;
    if (t < 37) {
        float x = (float)(t - 18);
        if (fabsf(x) <= fs) {
            float qq = x / sd;
            e = __expf(-0.5f * qq * qq);
            c = -x / (sd * sd * sd * 6.28318530717958647692f) * e;
        }
    }
    __shared__ float sa[40], sb[40];
    if (t < 37) { sa[t] = e; sb[t] = fabsf(c); }
    __syncthreads();
    __shared__ float Se, Sc;
    if (t == 0) {
        float a = 0.f, d = 0.f;
        for (int i = 0; i < 37; i++) { a += sa[i]; d += sb[i]; }
        Se = a; Sc = d;
    }
    __syncthreads();
    if (t < 37) {
        wsf[OFF_EH + b * 37 + t] = e / Se;
        wsf[OFF_CH + b * 37 + t] = c / Sc;
    }
}

// ---------------- horizontal pass: batch -> xg (on the fly) -> t0..t3 ----------------
// Round-4 (kept): coefficients staged in LDS; 40-tap loop split prologue(3)/main(34,
// guard-free, sliding coefficient window)/epilogue(3).
__device__ __forceinline__ int skw(int c) { return c + (c >> 5); }
__global__ __launch_bounds__(256, 4) void horiz_kernel(const float* __restrict__ batch,
                                                       const float* __restrict__ gcm,
                                                       const float* __restrict__ ehat,
                                                       const float* __restrict__ chat,
                                                       float* __restrict__ t) {
    __shared__ float xr[2][3][566];        // skewed: logical col 0..547 -> skw(c)
    __shared__ float cE[40], cC[40];
    int tx = threadIdx.x;
    int h0 = blockIdx.x * 2;
    int b  = blockIdx.y;
    if (tx < 37) { cE[tx] = ehat[b * 37 + tx]; cC[tx] = chat[b * 37 + tx]; }
    const float* pb = batch + (size_t)(b * 3) * PIX;
    float g0 = gcm[0], g1 = gcm[1], g2 = gcm[2];
    float g3 = gcm[3], g4 = gcm[4], g5 = gcm[5];
    float g6 = gcm[6], g7 = gcm[7], g8 = gcm[8];
    for (int i = tx; i < 2 * 548; i += 256) {
        int r = i / 548, c = i - r * 548;
        int gw = c - 18;
        float v0 = 0.f, v1 = 0.f, v2 = 0.f;
        if (gw >= 0 && gw < WW) {
            size_t p = (size_t)(h0 + r) * WW + gw;
            v0 = pb[p]; v1 = pb[(size_t)PIX + p]; v2 = pb[2 * (size_t)PIX + p];
        }
        int cs = skw(c);
        xr[r][0][cs] = g0 * v0 + g1 * v1 + g2 * v2;
        xr[r][1][cs] = g3 * v0 + g4 * v1 + g5 * v2;
        xr[r][2][cs] = g6 * v0 + g7 * v1 + g8 * v2;
    }
    __syncthreads();
    int r = tx >> 7, colbase = (tx & 127) * 4;
    float a0[4] = {}, a1[4] = {}, a2[4] = {}, a3[4] = {};
    float e1, e2, e3, d1, d2, d3;
    {   // prologue kk = 0..2 (i <= kk), seeds the coefficient window
        float ce[3], cc2[3];
#pragma unroll
        for (int k = 0; k < 3; k++) { ce[k] = cE[k]; cc2[k] = cC[k]; }
#pragma unroll
        for (int kk = 0; kk < 3; kk++) {
            int cs = skw(colbase + kk);
            float x0 = xr[r][0][cs], x1 = xr[r][1][cs], x2 = xr[r][2][cs];
#pragma unroll
            for (int i = 0; i < 3; i++) {
                if (i <= kk) {
                    float ce_ = ce[kk - i], cc_ = cc2[kk - i];
                    a0[i] += ce_ * x0; a1[i] += ce_ * x1;
                    a2[i] += ce_ * x2; a3[i] += cc_ * x0;
                }
            }
        }
        e1 = ce[2]; e2 = ce[1]; e3 = ce[0];
        d1 = cc2[2]; d2 = cc2[1]; d3 = cc2[0];
    }
#pragma unroll 2
    for (int kk = 3; kk < 37; kk++) {      // main: all 4 outputs valid, no guards
        float e0 = cE[kk], d0 = cC[kk];
        int cs = skw(colbase + kk);
        float x0 = xr[r][0][cs], x1 = xr[r][1][cs], x2 = xr[r][2][cs];
        a0[0] += e0 * x0; a1[0] += e0 * x1; a2[0] += e0 * x2; a3[0] += d0 * x0;
        a0[1] += e1 * x0; a1[1] += e1 * x1; a2[1] += e1 * x2; a3[1] += d1 * x0;
        a0[2] += e2 * x0; a1[2] += e2 * x1; a2[2] += e2 * x2; a3[2] += d2 * x0;
        a0[3] += e3 * x0; a1[3] += e3 * x1; a2[3] += e3 * x2; a3[3] += d3 * x0;
        e3 = e2; e2 = e1; e1 = e0; d3 = d2; d2 = d1; d1 = d0;
    }
    {   // kk = 37 (e1=cE[36], e2=cE[35], e3=cE[34])
        int cs = skw(colbase + 37);
        float x0 = xr[r][0][cs], x1 = xr[r][1][cs], x2 = xr[r][2][cs];
        a0[1] += e1 * x0; a1[1] += e1 * x1; a2[1] += e1 * x2; a3[1] += d1 * x0;
        a0[2] += e2 * x0; a1[2] += e2 * x1; a2[2] += e2 * x2; a3[2] += d2 * x0;
        a0[3] += e3 * x0; a1[3] += e3 * x1; a2[3] += e3 * x2; a3[3] += d3 * x0;
    }
    {   // kk = 38
        int cs = skw(colbase + 38);
        float x0 = xr[r][0][cs], x1 = xr[r][1][cs], x2 = xr[r][2][cs];
        a0[2] += e1 * x0; a1[2] += e1 * x1; a2[2] += e1 * x2; a3[2] += d1 * x0;
        a0[3] += e2 * x0; a1[3] += e2 * x1; a2[3] += e2 * x2; a3[3] += d2 * x0;
    }
    {   // kk = 39
        int cs = skw(colbase + 39);
        float x0 = xr[r][0][cs], x1 = xr[r][1][cs], x2 = xr[r][2][cs];
        a0[3] += e1 * x0; a1[3] += e1 * x1; a2[3] += e1 * x2; a3[3] += d1 * x0;
    }
    const size_t PL = (size_t)BN * PIX;
    size_t p = (size_t)b * PIX + (size_t)(h0 + r) * WW + colbase;
    *(float4*)&t[0 * PL + p] = make_float4(a0[0], a0[1], a0[2], a0[3]);
    *(float4*)&t[1 * PL + p] = make_float4(a1[0], a1[1], a1[2], a1[3]);
    *(float4*)&t[2 * PL + p] = make_float4(a2[0], a2[1], a2[2], a2[3]);
    *(float4*)&t[3 * PL + p] = make_float4(a3[0], a3[1], a3[2], a3[3]);
}

// ---------------- vertical pass + final math -> out ch0,1,5 (4-row sliding/thread) ----------------
// Round-4 (kept): LDS coefficients, guard-free main loop with pointer-increment
// addressing, wave-uniform safe-path (30/32 y-blocks never touch the border).
#define VACC(ee, dd, ii) { E[ii] += (ee) * v0; Ex[ii] += (dd) * v0; Ey[ii] += (ee) * v3; \
                           El[ii] += (ee) * v1; Ell[ii] += (ee) * v2; }
__global__ __launch_bounds__(256, 4) void vert_kernel(const float* __restrict__ t,
                                                      const float* __restrict__ ehat,
                                                      const float* __restrict__ chat,
                                                      float* __restrict__ out) {
    __shared__ float cE[40], cC[40];
    int tx = threadIdx.x;
    int b = blockIdx.z;
    if (tx < 37) { cE[tx] = ehat[b * 37 + tx]; cC[tx] = chat[b * 37 + tx]; }
    int j = blockIdx.x * 64 + (tx & 63);
    int r0 = (blockIdx.y * 4 + (tx >> 6)) * 4;
    const size_t PL = (size_t)BN * PIX;
    const float* t0 = t + (size_t)b * PIX;
    __syncthreads();
    float E[4] = {}, Ex[4] = {}, Ey[4] = {}, El[4] = {}, Ell[4] = {};
    bool safe = (r0 >= 18) && (r0 <= HH - 22);       // all 40 rows in-range (wave-uniform)
    float e1, e2, e3, d1, d2, d3;
    {   // prologue kk = 0..2
        float ce[3], cc2[3];
#pragma unroll
        for (int k = 0; k < 3; k++) { ce[k] = cE[k]; cc2[k] = cC[k]; }
#pragma unroll
        for (int kk = 0; kk < 3; kk++) {
            int gr = r0 - 18 + kk;
            float v0 = 0.f, v1 = 0.f, v2 = 0.f, v3 = 0.f;
            if ((unsigned)gr < (unsigned)HH) {
                size_t idx = (size_t)gr * WW + j;
                v0 = t0[idx]; v1 = t0[PL + idx]; v2 = t0[2 * PL + idx]; v3 = t0[3 * PL + idx];
            }
#pragma unroll
            for (int i = 0; i < 3; i++) {
                if (i <= kk) {
                    float ee = ce[kk - i], dd = cc2[kk - i];
                    VACC(ee, dd, i)
                }
            }
        }
        e1 = ce[2]; e2 = ce[1]; e3 = ce[0];
        d1 = cc2[2]; d2 = cc2[1]; d3 = cc2[0];
    }
    const float* pv = t0 + (size_t)(r0 - 15) * WW + j;   // row at kk=3
    if (safe) {
#pragma unroll 2
        for (int kk = 3; kk < 37; kk++) {
            float e0 = cE[kk], d0 = cC[kk];
            float v0 = pv[0], v1 = pv[PL], v2 = pv[2 * PL], v3 = pv[3 * PL];
            VACC(e0, d0, 0) VACC(e1, d1, 1) VACC(e2, d2, 2) VACC(e3, d3, 3)
            e3 = e2; e2 = e1; e1 = e0; d3 = d2; d2 = d1; d1 = d0;
            pv += WW;
        }
    } else {
        int gr = r0 - 15;
#pragma unroll 2
        for (int kk = 3; kk < 37; kk++) {
            float e0 = cE[kk], d0 = cC[kk];
            float v0 = 0.f, v1 = 0.f, v2 = 0.f, v3 = 0.f;
            if ((unsigned)gr < (unsigned)HH) {
                v0 = pv[0]; v1 = pv[PL]; v2 = pv[2 * PL]; v3 = pv[3 * PL];
            }
            VACC(e0, d0, 0) VACC(e1, d1, 1) VACC(e2, d2, 2) VACC(e3, d3, 3)
            e3 = e2; e2 = e1; e1 = e0; d3 = d2; d2 = d1; d1 = d0;
            pv += WW; gr++;
        }
    }
    // epilogue kk = 37..39 (e1=cE[36], e2=cE[35], e3=cE[34]; no rotation)
#pragma unroll
    for (int kk = 37; kk < 40; kk++) {
        int gr = r0 - 18 + kk;                        // >= 19, may exceed 511
        float v0 = 0.f, v1 = 0.f, v2 = 0.f, v3 = 0.f;
        if (gr < HH) {
            size_t idx = (size_t)gr * WW + j;
            v0 = t0[idx]; v1 = t0[PL + idx]; v2 = t0[2 * PL + idx]; v3 = t0[3 * PL + idx];
        }
        if (kk == 37) { VACC(e1, d1, 1) VACC(e2, d2, 2) VACC(e3, d3, 3) }
        if (kk == 38) { VACC(e1, d1, 2) VACC(e2, d2, 3) }
        if (kk == 39) { VACC(e1, d1, 3) }
    }
#pragma unroll
    for (int i = 0; i < 4; i++) {
        int h = r0 + i;
        float Hf = atanf(El[i] / (Ell[i] + EPSF));
        float S = logf((El[i] * El[i] + Ell[i] * Ell[i]) / (E[i] * E[i] + EPSF) + EPSF);
        float rx = Ex[i] / (E[i] + EPSF), ry = Ey[i] / (E[i] + EPSF);
        float Wv = atanf(rx * rx + ry * ry);
        size_t base = (size_t)(b * 6) * PIX + (size_t)h * WW + j;
        out[base] = Hf;
        out[base + PIX] = S;
        out[base + 5 * (size_t)PIX] = Wv;
    }
}
#undef VACC

extern "C" void kernel_launch(void* const* d_in, const int* in_sizes, int n_in,
                              void* d_out, int out_size, void* d_ws, size_t ws_size,
                              hipStream_t stream) {
    const float* batch = (const float*)d_in[0];
    const float* gcm   = (const float*)d_in[1];
    const float* w1    = (const float*)d_in[2];
    const float* b1    = (const float*)d_in[3];
    const float* w2    = (const float*)d_in[4];
    const float* b2    = (const float*)d_in[5];
    const float* w3    = (const float*)d_in[6];
    const float* b3    = (const float*)d_in[7];
    float* out = (float*)d_out;

    if (ws_size < WS_NEEDED) return;

    float* wsf = (float*)d_ws;
    float* tpl = (float*)((char*)d_ws + OFF_TPB);
    float* ehat = wsf + OFF_EH;
    float* chat = wsf + OFF_CH;

    prep_kernel<<<dim3(1), dim3(256), 0, stream>>>(w1, w2, wsf);
    conv12_kernel<<<dim3(8, 64, 8), dim3(256), 0, stream>>>(
        batch, (const unsigned short*)(wsf + OFF_W1R), b1,
        (const unsigned short*)(wsf + OFF_WR), b2, wsf, out);
    filter_kernel<<<dim3(8), dim3(160), 0, stream>>>(w3, b3, wsf);
    horiz_kernel<<<dim3(256, 8), dim3(256), 0, stream>>>(batch, gcm, ehat, chat, tpl);
    vert_kernel<<<dim3(8, 32, 8), dim3(256), 0, stream>>>(tpl, ehat, chat, out);
}

// Round 6
// 233.043 us; speedup vs baseline: 1.1112x; 1.0427x over previous
//
#include <hip/hip_runtime.h>
#include <hip/hip_bf16.h>

constexpr int BN = 8, HH = 512, WW = 512;
constexpr int PIX = HH * WW;
constexpr float EPSF = 1e-4f;

__device__ __forceinline__ float b2f(__hip_bfloat16 x) { return __bfloat162float(x); }
__device__ __forceinline__ __hip_bfloat16 f2b(float x) { return __float2bfloat16(x); }
__device__ __forceinline__ unsigned short bfbits(float x) {
    union { __hip_bfloat16 b; unsigned short u; } cv; cv.b = f2b(x); return cv.u;
}
// hardware packed f32->bf16 (RNE): D = {hi:cvt(S1), lo:cvt(S0)}
__device__ __forceinline__ unsigned int cvtpk(float lo, float hi) {
    unsigned int r;
    asm("v_cvt_pk_bf16_f32 %0, %1, %2" : "=v"(r) : "v"(lo), "v"(hi));
    return r;
}
// silu via hw rcp (h is bf16-quantized downstream; ~2^-22 rel err invisible)
__device__ __forceinline__ float silu(float a) {
    return a * __builtin_amdgcn_rcpf(1.f + __expf(-a));
}

typedef __attribute__((ext_vector_type(8))) short bf16x8;   // MFMA A/B frag (4 VGPRs)
typedef __attribute__((ext_vector_type(4))) float f32x4;    // MFMA C/D frag

// ---- workspace float offsets (small region) ----
constexpr int OFF_TOT = 0;       // 8*16 per-image channel totals (atomics)
constexpr int OFF_ROW0 = 128;
constexpr int OFF_ROW1 = 256;
constexpr int OFF_COL0 = 384;
constexpr int OFF_COL1 = 512;
constexpr int OFF_COR = 640;     // corners [b][hi][wi][16] -> 640..1151
constexpr int OFF_W1R = 1280;    // w1 A-frags hi(512 bf16)+lo(512 bf16) = 512 floats
constexpr int OFF_WR  = 2048;    // w2 A-frags hi(2560 bf16) + lo(2560 bf16)
constexpr int OFF_EH  = 4608;    // 8*37
constexpr int OFF_CH  = 5120;    // 8*37
// ---- big buffers: only tpl (xg computed on the fly in horiz) ----
constexpr size_t OFF_TPB = 65536;                          // tpl fp32 (4 planes)
constexpr size_t TP_BYTES = (size_t)4 * BN * PIX * 4;      // 33,554,432
constexpr size_t WS_NEEDED = OFF_TPB + TP_BYTES;           // ~33.6 MB (134 MB proven)

// ---------------- prep: zero atomic slots, swizzle w1/w2 into hi/lo A-fragments ----------------
// hi = rn-bf16(w), lo = rn-bf16(w - hi): split keeps the ceil(3sd+0.5) path at ~fp32 accuracy
// (bf16-only weights flip the discontinuity -> pi-flips in Hf).
__global__ void prep_kernel(const float* __restrict__ w1, const float* __restrict__ w2,
                            float* __restrict__ wsf) {
    int t = threadIdx.x;
    for (int i = t; i < 640; i += 256) wsf[i] = 0.f;
    // w2 A-frags (conv2): A[oc][k], k = (tap_local)*16 + ic within each K=32 chunk ks
    unsigned short* ab = (unsigned short*)(wsf + OFF_WR);
    for (int idx = t; idx < 5120; idx += 256) {
        int part = idx / 2560;               // 0 = hi, 1 = lo
        int id = idx - part * 2560;
        int ks = id >> 9, rem = id & 511, lane = rem >> 3, j = id & 7;
        int oc = lane & 15, q = lane >> 4;
        int k = q * 8 + j;
        int tap = 2 * ks + (k >> 4), ic = k & 15;
        float val = (tap <= 8) ? w2[oc * 144 + ic * 9 + tap] : 0.f;
        float hv = b2f(f2b(val));
        ab[idx] = (part == 0) ? bfbits(val) : bfbits(val - hv);
    }
    // w1 A-frags (conv1): A[oc][k], k = ic*9 + kh*3 + kw (0..26), pad to 32 with zeros
    unsigned short* a1 = (unsigned short*)(wsf + OFF_W1R);
    for (int idx = t; idx < 1024; idx += 256) {
        int part = idx >> 9;                 // 0 = hi, 1 = lo
        int id = idx & 511;
        int lane = id >> 3, j = id & 7;
        int oc = lane & 15, q = lane >> 4;
        int k = q * 8 + j;
        float val = (k < 27) ? w1[oc * 27 + k] : 0.f;
        float hv = b2f(f2b(val));
        a1[idx] = (part == 0) ? bfbits(val) : bfbits(val - hv);
    }
}

// ---------------- fused conv1(MFMA)+conv2(MFMA)+RGB with conv3-mean reduction ----------------
// Round-6: latency-hiding push. (a) batch halo staged as BF16 pairs (identical values to
// the old gather-then-cvtpk; LDS 31.2->26.3 KB => 6 blocks/CU); RGB reads global fp32
// directly (exact compares). (b) conv1 group loop 2-deep software-pipelined: next group's
// 8 LDS gathers issue before the current pack->MFMA->silu->write chain. Uniform 11-trip
// loop: clamped overflow groups rewrite slot 659 with identical data (benign).
// CRITICAL: h1 pixels OUTSIDE the image must be exactly 0 (conv2's zero padding);
// padded-K B halves masked to 0 (A=0 there, but NaN*0=NaN in MFMA).
__global__ __launch_bounds__(256) void conv12_kernel(const float* __restrict__ batch,
                                                     const unsigned short* __restrict__ w1buf,
                                                     const float* __restrict__ b1,
                                                     const unsigned short* __restrict__ abuf,
                                                     const float* __restrict__ b2v,
                                                     float* __restrict__ wsf,
                                                     float* __restrict__ out) {
    __shared__ unsigned short stb[3][12][68];   // batch halo bf16: rows h0-2..h0+9, cols w0-2..w0+65
    __shared__ uint4 h1s[10 * 66 * 2];
    __shared__ float part[4][16];

    int tx = threadIdx.x;
    int lane = tx & 63, wave = tx >> 6;
    int n = lane & 15, q = lane >> 4;
    int w0 = blockIdx.x * 64, h0 = blockIdx.y * 8, b = blockIdx.z;

    union { uint4 u; bf16x8 v; } cv;
    const float* pb = batch + (size_t)(b * 3) * PIX;

    // ---- stage batch halo tile into LDS as bf16 pairs (1224 u32 writes) ----
    unsigned int* stw = (unsigned int*)&stb[0][0][0];
    for (int i = tx; i < 1224; i += 256) {           // 3 ch * 12 rows * 34 pairs
        int ch = i / 408, rem = i - ch * 408;
        int r = rem / 34, c2 = rem - r * 34;
        int gh = h0 - 2 + r, gw = w0 - 2 + 2 * c2;
        const float* p = pb + (size_t)ch * PIX + (size_t)gh * WW;
        bool rok = (gh >= 0) && (gh < HH);
        float v0 = (rok && gw >= 0 && gw < WW) ? p[gw] : 0.f;
        float v1 = (rok && gw + 1 >= 0 && gw + 1 < WW) ? p[gw + 1] : 0.f;
        stw[i] = cvtpk(v0, v1);
    }

    // per-lane conv1 constants (independent of groups)
    bf16x8 w1h, w1l;
    const uint4* w14 = (const uint4*)w1buf;
    cv.u = w14[lane];      w1h = cv.v;
    cv.u = w14[64 + lane]; w1l = cv.v;
    int koff[8];
#pragma unroll
    for (int j = 0; j < 8; j++) {
        int k = q * 8 + j;
        int kk = (k < 27) ? k : 0;
        int ic = kk / 9, rem = kk - ic * 9, kh = rem / 3, kw = rem - kh * 3;
        koff[j] = ic * 816 + kh * 68 + kw;           // units: u16 elements
    }
    float b1q[4];
#pragma unroll
    for (int r = 0; r < 4; r++) b1q[r] = b1[q * 4 + r];
    bool hiq = (q == 3);
    __syncthreads();

    // ---- conv1 via MFMA over the 10x66 h1 halo, 2-deep pipelined gather ----
    const unsigned short* sptr = &stb[0][0][0];
    unsigned int* hw = (unsigned int*)h1s;
    int i_c = wave * 16 + n;                         // first group's pixel (always < 660)
    int r_c = (unsigned)i_c / 66u; int c_c = i_c - r_c * 66;
    int base_c = r_c * 68 + c_c;
    unsigned short x0 = sptr[base_c + koff[0]], x1 = sptr[base_c + koff[1]];
    unsigned short x2 = sptr[base_c + koff[2]], x3 = sptr[base_c + koff[3]];
    unsigned short x4 = sptr[base_c + koff[4]], x5 = sptr[base_c + koff[5]];
    unsigned short x6 = sptr[base_c + koff[6]], x7 = sptr[base_c + koff[7]];
    int g = wave;
    for (int gi = 0; gi < 11; gi++) {
        // issue next group's gathers first (latency hides under current compute)
        unsigned short y0 = 0, y1 = 0, y2 = 0, y3 = 0, y4 = 0, y5 = 0, y6 = 0, y7 = 0;
        int i_n = 0, c_n = 0;
        if (gi < 10) {
            i_n = (g + 4) * 16 + n; if (i_n > 659) i_n = 659;   // clamp: dup-write same data
            int r_n = (unsigned)i_n / 66u; c_n = i_n - r_n * 66;
            int base_n = r_n * 68 + c_n;
            y0 = sptr[base_n + koff[0]]; y1 = sptr[base_n + koff[1]];
            y2 = sptr[base_n + koff[2]]; y3 = sptr[base_n + koff[3]];
            y4 = sptr[base_n + koff[4]]; y5 = sptr[base_n + koff[5]];
            y6 = sptr[base_n + koff[6]]; y7 = sptr[base_n + koff[7]];
        }
        // compute current group
        union { unsigned int w[4]; bf16x8 v; } bb;
        bb.w[0] = (unsigned int)x0 | ((unsigned int)x1 << 16);
        bb.w[1] = (unsigned int)x2 | ((unsigned int)x3 << 16);
        bb.w[2] = (unsigned int)x4 | ((unsigned int)x5 << 16);
        bb.w[3] = (unsigned int)x6 | ((unsigned int)x7 << 16);
        if (hiq) {                                   // q==3: k=27..31 padded -> zero
            bb.w[1] &= 0xFFFFu; bb.w[2] = 0u; bb.w[3] = 0u;
        }
        f32x4 a = {0, 0, 0, 0};
        a = __builtin_amdgcn_mfma_f32_16x16x32_bf16(w1h, bb.v, a, 0, 0, 0);
        a = __builtin_amdgcn_mfma_f32_16x16x32_bf16(w1l, bb.v, a, 0, 0, 0);
        int rr_ = (unsigned)i_c / 66u;               // cheap re-derive for bounds
        int gh = h0 - 1 + rr_, gw = w0 - 1 + c_c;
        bool ok = ((unsigned)gh < (unsigned)HH) && ((unsigned)gw < (unsigned)WW);
        unsigned int p0 = cvtpk(silu(a[0] + b1q[0]), silu(a[1] + b1q[1]));
        unsigned int p1 = cvtpk(silu(a[2] + b1q[2]), silu(a[3] + b1q[3]));
        p0 = ok ? p0 : 0u;                           // conv2 zero padding
        p1 = ok ? p1 : 0u;
        int swz = (c_c >> 2) & 1;
        int slot = i_c * 2 + ((q >= 2) ? (swz ^ 1) : swz);
        *(uint2*)&hw[slot * 4 + (q & 1) * 2] = make_uint2(p0, p1);
        // rotate pipeline
        x0 = y0; x1 = y1; x2 = y2; x3 = y3; x4 = y4; x5 = y5; x6 = y6; x7 = y7;
        i_c = i_n; c_c = c_n;
        g += 4;
    }

    // ---- RGB order channels, inputs from global fp32 (L2-hot, exact compares) ----
    for (int j = tx; j < 512; j += 256) {
        int rr = j >> 6, ccx = j & 63;
        size_t p = (size_t)(h0 + rr) * WW + (w0 + ccx);
        float v0 = pb[p], v1 = pb[(size_t)PIX + p], v2 = pb[2 * (size_t)PIX + p];
        int mx  = (v0 >= v1 && v0 >= v2) ? 0 : ((v1 >= v2) ? 1 : 2);
        int mx2 = (v2 >= v1 && v2 >= v0) ? 2 : ((v1 >= v0) ? 1 : 0);
        int mn  = (v0 <= v1 && v0 <= v2) ? 0 : ((v1 <= v2) ? 1 : 2);
        int mn2 = (v2 <= v1 && v2 <= v0) ? 2 : ((v1 <= v0) ? 1 : 0);
#pragma unroll
        for (int c = 0; c < 3; c++) {
            float r = 0.5f * ((float)(c == mx) + (float)(c == mx2))
                    - 0.5f * ((float)(c == mn) + (float)(c == mn2));
            out[(size_t)(b * 6 + 2 + c) * PIX + p] = r;
        }
    }
    __syncthreads();

    // ---- conv2 via MFMA + silu + conv3-mean reductions ----
    bf16x8 ah[5], al[5];
    const uint4* ab4 = (const uint4*)abuf;
#pragma unroll
    for (int ks = 0; ks < 5; ks++) {
        cv.u = ab4[ks * 64 + lane];       ah[ks] = cv.v;
        cv.u = ab4[320 + ks * 64 + lane]; al[ks] = cv.v;
    }
    float b2q[4];
#pragma unroll
    for (int r = 0; r < 4; r++) b2q[r] = b2v[q * 4 + r];

    float tt[4] = {0, 0, 0, 0};
    float cs0[4] = {0, 0, 0, 0};
    float cs1[4] = {0, 0, 0, 0};
    for (int rloc = 0; rloc < 2; rloc++) {
        int row = wave * 2 + rloc;
        int grow = h0 + row;
        f32x4 acc[4] = {{0,0,0,0},{0,0,0,0},{0,0,0,0},{0,0,0,0}};
#pragma unroll
        for (int ks = 0; ks < 5; ks++) {
            int tap = 2 * ks + (q >> 1); if (tap > 8) tap = 8;
            int dh = tap / 3 - 1, dw = tap % 3 - 1;
            int half = q & 1;
            int lr = row + 1 + dh;
#pragma unroll
            for (int t = 0; t < 4; t++) {
                int c = 1 + dw + t * 16 + n;
                cv.u = h1s[(lr * 66 + c) * 2 + (half ^ ((c >> 2) & 1))];
                acc[t] = __builtin_amdgcn_mfma_f32_16x16x32_bf16(ah[ks], cv.v, acc[t], 0, 0, 0);
                acc[t] = __builtin_amdgcn_mfma_f32_16x16x32_bf16(al[ks], cv.v, acc[t], 0, 0, 0);
            }
        }
        float sv[4][4];
#pragma unroll
        for (int t = 0; t < 4; t++)
#pragma unroll
            for (int r = 0; r < 4; r++)
                sv[t][r] = silu(acc[t][r] + b2q[r]);
#pragma unroll
        for (int r = 0; r < 4; r++) tt[r] += sv[0][r] + sv[1][r] + sv[2][r] + sv[3][r];
        if (grow == 0 || grow == HH - 1) {
            int off = (grow == 0) ? OFF_ROW0 : OFF_ROW1;
#pragma unroll
            for (int r = 0; r < 4; r++) {
                float x = sv[0][r] + sv[1][r] + sv[2][r] + sv[3][r];
#pragma unroll
                for (int d = 1; d < 16; d <<= 1) x += __shfl_xor(x, d, 64);
                if (n == 0) atomicAdd(&wsf[off + b * 16 + q * 4 + r], x);
            }
        }
        if (blockIdx.x == 0 && n == 0)
#pragma unroll
            for (int r = 0; r < 4; r++) cs0[r] += sv[0][r];
        if (blockIdx.x == 7 && n == 15)
#pragma unroll
            for (int r = 0; r < 4; r++) cs1[r] += sv[3][r];
        if ((grow == 0 || grow == HH - 1)) {
            int hi = (grow == 0) ? 0 : 1;
            if (blockIdx.x == 0 && n == 0)
#pragma unroll
                for (int r = 0; r < 4; r++)
                    wsf[OFF_COR + ((b * 2 + hi) * 2 + 0) * 16 + q * 4 + r] = sv[0][r];
            if (blockIdx.x == 7 && n == 15)
#pragma unroll
                for (int r = 0; r < 4; r++)
                    wsf[OFF_COR + ((b * 2 + hi) * 2 + 1) * 16 + q * 4 + r] = sv[3][r];
        }
    }
    if (blockIdx.x == 0 && n == 0)
#pragma unroll
        for (int r = 0; r < 4; r++) atomicAdd(&wsf[OFF_COL0 + b * 16 + q * 4 + r], cs0[r]);
    if (blockIdx.x == 7 && n == 15)
#pragma unroll
        for (int r = 0; r < 4; r++) atomicAdd(&wsf[OFF_COL1 + b * 16 + q * 4 + r], cs1[r]);
#pragma unroll
    for (int r = 0; r < 4; r++) {
        float x = tt[r];
#pragma unroll
        for (int d = 1; d < 16; d <<= 1) x += __shfl_xor(x, d, 64);
        tt[r] = x;
    }
    if (n == 0)
#pragma unroll
        for (int r = 0; r < 4; r++) part[wave][q * 4 + r] = tt[r];
    __syncthreads();
    if (tx < 16)
        atomicAdd(&wsf[OFF_TOT + b * 16 + tx],
                  part[0][tx] + part[1][tx] + part[2][tx] + part[3][tx]);
}

// ---------------- filter: assemble mean via edge algebra, build separable taps ----------------
__global__ void filter_kernel(const float* __restrict__ w3, const float* __restrict__ b3,
                              float* __restrict__ wsf) {
    int b = blockIdx.x, t = threadIdx.x;   // 160 threads
    __shared__ float red[160];
    float val = 0.f;
    if (t < 144) {
        int ic = t / 9, tap = t % 9, kh = tap / 3, kw = tap % 3;
        float T = wsf[OFF_TOT + b * 16 + ic];
        int hi = -1, wi = -1;
        if (kh == 0) { T -= wsf[OFF_ROW1 + b * 16 + ic]; hi = 1; }
        else if (kh == 2) { T -= wsf[OFF_ROW0 + b * 16 + ic]; hi = 0; }
        if (kw == 0) { T -= wsf[OFF_COL1 + b * 16 + ic]; wi = 1; }
        else if (kw == 2) { T -= wsf[OFF_COL0 + b * 16 + ic]; wi = 0; }
        if (hi >= 0 && wi >= 0) T += wsf[OFF_COR + ((b * 2 + hi) * 2 + wi) * 16 + ic];
        val = w3[t] * T;
    }
    red[t] = val;
    __syncthreads();
    __shared__ float sh_mean;
    if (t == 0) {
        float S = 0.f;
        for (int i = 0; i < 144; i++) S += red[i];
        sh_mean = b3[0] + S * (1.f / (float)PIX);
    }
    __syncthreads();
    float scale = fminf(2.5f, fmaxf(-2.5f, sh_mean));
    float sd = exp2f(scale);
    float fs = ceilf(3.f * sd + 0.5f);
    float e = 0.f, c = 0.f;
    if (t < 37) {
        float x = (float)(t - 18);
        if (fabsf(x) <= fs) {
            float qq = x / sd;
            e = __expf(-0.5f * qq * qq);
            c = -x / (sd * sd * sd * 6.28318530717958647692f) * e;
        }
    }
    __shared__ float sa[40], sb[40];
    if (t < 37) { sa[t] = e; sb[t] = fabsf(c); }
    __syncthreads();
    __shared__ float Se, Sc;
    if (t == 0) {
        float a = 0.f, d = 0.f;
        for (int i = 0; i < 37; i++) { a += sa[i]; d += sb[i]; }
        Se = a; Sc = d;
    }
    __syncthreads();
    if (t < 37) {
        wsf[OFF_EH + b * 37 + t] = e / Se;
        wsf[OFF_CH + b * 37 + t] = c / Sc;
    }
}

// ---------------- horizontal pass: batch -> xg (on the fly) -> t0..t3 ----------------
// Round-4 (kept): coefficients staged in LDS; 40-tap loop split prologue(3)/main(34,
// guard-free, sliding coefficient window)/epilogue(3).
__device__ __forceinline__ int skw(int c) { return c + (c >> 5); }
__global__ __launch_bounds__(256, 4) void horiz_kernel(const float* __restrict__ batch,
                                                       const float* __restrict__ gcm,
                                                       const float* __restrict__ ehat,
                                                       const float* __restrict__ chat,
                                                       float* __restrict__ t) {
    __shared__ float xr[2][3][566];        // skewed: logical col 0..547 -> skw(c)
    __shared__ float cE[40], cC[40];
    int tx = threadIdx.x;
    int h0 = blockIdx.x * 2;
    int b  = blockIdx.y;
    if (tx < 37) { cE[tx] = ehat[b * 37 + tx]; cC[tx] = chat[b * 37 + tx]; }
    const float* pb = batch + (size_t)(b * 3) * PIX;
    float g0 = gcm[0], g1 = gcm[1], g2 = gcm[2];
    float g3 = gcm[3], g4 = gcm[4], g5 = gcm[5];
    float g6 = gcm[6], g7 = gcm[7], g8 = gcm[8];
    for (int i = tx; i < 2 * 548; i += 256) {
        int r = i / 548, c = i - r * 548;
        int gw = c - 18;
        float v0 = 0.f, v1 = 0.f, v2 = 0.f;
        if (gw >= 0 && gw < WW) {
            size_t p = (size_t)(h0 + r) * WW + gw;
            v0 = pb[p]; v1 = pb[(size_t)PIX + p]; v2 = pb[2 * (size_t)PIX + p];
        }
        int cs = skw(c);
        xr[r][0][cs] = g0 * v0 + g1 * v1 + g2 * v2;
        xr[r][1][cs] = g3 * v0 + g4 * v1 + g5 * v2;
        xr[r][2][cs] = g6 * v0 + g7 * v1 + g8 * v2;
    }
    __syncthreads();
    int r = tx >> 7, colbase = (tx & 127) * 4;
    float a0[4] = {}, a1[4] = {}, a2[4] = {}, a3[4] = {};
    float e1, e2, e3, d1, d2, d3;
    {   // prologue kk = 0..2 (i <= kk), seeds the coefficient window
        float ce[3], cc2[3];
#pragma unroll
        for (int k = 0; k < 3; k++) { ce[k] = cE[k]; cc2[k] = cC[k]; }
#pragma unroll
        for (int kk = 0; kk < 3; kk++) {
            int cs = skw(colbase + kk);
            float x0 = xr[r][0][cs], x1 = xr[r][1][cs], x2 = xr[r][2][cs];
#pragma unroll
            for (int i = 0; i < 3; i++) {
                if (i <= kk) {
                    float ce_ = ce[kk - i], cc_ = cc2[kk - i];
                    a0[i] += ce_ * x0; a1[i] += ce_ * x1;
                    a2[i] += ce_ * x2; a3[i] += cc_ * x0;
                }
            }
        }
        e1 = ce[2]; e2 = ce[1]; e3 = ce[0];
        d1 = cc2[2]; d2 = cc2[1]; d3 = cc2[0];
    }
#pragma unroll 2
    for (int kk = 3; kk < 37; kk++) {      // main: all 4 outputs valid, no guards
        float e0 = cE[kk], d0 = cC[kk];
        int cs = skw(colbase + kk);
        float x0 = xr[r][0][cs], x1 = xr[r][1][cs], x2 = xr[r][2][cs];
        a0[0] += e0 * x0; a1[0] += e0 * x1; a2[0] += e0 * x2; a3[0] += d0 * x0;
        a0[1] += e1 * x0; a1[1] += e1 * x1; a2[1] += e1 * x2; a3[1] += d1 * x0;
        a0[2] += e2 * x0; a1[2] += e2 * x1; a2[2] += e2 * x2; a3[2] += d2 * x0;
        a0[3] += e3 * x0; a1[3] += e3 * x1; a2[3] += e3 * x2; a3[3] += d3 * x0;
        e3 = e2; e2 = e1; e1 = e0; d3 = d2; d2 = d1; d1 = d0;
    }
    {   // kk = 37 (e1=cE[36], e2=cE[35], e3=cE[34])
        int cs = skw(colbase + 37);
        float x0 = xr[r][0][cs], x1 = xr[r][1][cs], x2 = xr[r][2][cs];
        a0[1] += e1 * x0; a1[1] += e1 * x1; a2[1] += e1 * x2; a3[1] += d1 * x0;
        a0[2] += e2 * x0; a1[2] += e2 * x1; a2[2] += e2 * x2; a3[2] += d2 * x0;
        a0[3] += e3 * x0; a1[3] += e3 * x1; a2[3] += e3 * x2; a3[3] += d3 * x0;
    }
    {   // kk = 38
        int cs = skw(colbase + 38);
        float x0 = xr[r][0][cs], x1 = xr[r][1][cs], x2 = xr[r][2][cs];
        a0[2] += e1 * x0; a1[2] += e1 * x1; a2[2] += e1 * x2; a3[2] += d1 * x0;
        a0[3] += e2 * x0; a1[3] += e2 * x1; a2[3] += e2 * x2; a3[3] += d2 * x0;
    }
    {   // kk = 39
        int cs = skw(colbase + 39);
        float x0 = xr[r][0][cs], x1 = xr[r][1][cs], x2 = xr[r][2][cs];
        a0[3] += e1 * x0; a1[3] += e1 * x1; a2[3] += e1 * x2; a3[3] += d1 * x0;
    }
    const size_t PL = (size_t)BN * PIX;
    size_t p = (size_t)b * PIX + (size_t)(h0 + r) * WW + colbase;
    *(float4*)&t[0 * PL + p] = make_float4(a0[0], a0[1], a0[2], a0[3]);
    *(float4*)&t[1 * PL + p] = make_float4(a1[0], a1[1], a1[2], a1[3]);
    *(float4*)&t[2 * PL + p] = make_float4(a2[0], a2[1], a2[2], a2[3]);
    *(float4*)&t[3 * PL + p] = make_float4(a3[0], a3[1], a3[2], a3[3]);
}

// ---------------- vertical pass + final math -> out ch0,1,5 (4-row sliding/thread) ----------------
// Round-4 (kept): LDS coefficients, guard-free main loop with pointer-increment
// addressing, wave-uniform safe-path (30/32 y-blocks never touch the border).
#define VACC(ee, dd, ii) { E[ii] += (ee) * v0; Ex[ii] += (dd) * v0; Ey[ii] += (ee) * v3; \
                           El[ii] += (ee) * v1; Ell[ii] += (ee) * v2; }
__global__ __launch_bounds__(256, 4) void vert_kernel(const float* __restrict__ t,
                                                      const float* __restrict__ ehat,
                                                      const float* __restrict__ chat,
                                                      float* __restrict__ out) {
    __shared__ float cE[40], cC[40];
    int tx = threadIdx.x;
    int b = blockIdx.z;
    if (tx < 37) { cE[tx] = ehat[b * 37 + tx]; cC[tx] = chat[b * 37 + tx]; }
    int j = blockIdx.x * 64 + (tx & 63);
    int r0 = (blockIdx.y * 4 + (tx >> 6)) * 4;
    const size_t PL = (size_t)BN * PIX;
    const float* t0 = t + (size_t)b * PIX;
    __syncthreads();
    float E[4] = {}, Ex[4] = {}, Ey[4] = {}, El[4] = {}, Ell[4] = {};
    bool safe = (r0 >= 18) && (r0 <= HH - 22);       // all 40 rows in-range (wave-uniform)
    float e1, e2, e3, d1, d2, d3;
    {   // prologue kk = 0..2
        float ce[3], cc2[3];
#pragma unroll
        for (int k = 0; k < 3; k++) { ce[k] = cE[k]; cc2[k] = cC[k]; }
#pragma unroll
        for (int kk = 0; kk < 3; kk++) {
            int gr = r0 - 18 + kk;
            float v0 = 0.f, v1 = 0.f, v2 = 0.f, v3 = 0.f;
            if ((unsigned)gr < (unsigned)HH) {
                size_t idx = (size_t)gr * WW + j;
                v0 = t0[idx]; v1 = t0[PL + idx]; v2 = t0[2 * PL + idx]; v3 = t0[3 * PL + idx];
            }
#pragma unroll
            for (int i = 0; i < 3; i++) {
                if (i <= kk) {
                    float ee = ce[kk - i], dd = cc2[kk - i];
                    VACC(ee, dd, i)
                }
            }
        }
        e1 = ce[2]; e2 = ce[1]; e3 = ce[0];
        d1 = cc2[2]; d2 = cc2[1]; d3 = cc2[0];
    }
    const float* pv = t0 + (size_t)(r0 - 15) * WW + j;   // row at kk=3
    if (safe) {
#pragma unroll 2
        for (int kk = 3; kk < 37; kk++) {
            float e0 = cE[kk], d0 = cC[kk];
            float v0 = pv[0], v1 = pv[PL], v2 = pv[2 * PL], v3 = pv[3 * PL];
            VACC(e0, d0, 0) VACC(e1, d1, 1) VACC(e2, d2, 2) VACC(e3, d3, 3)
            e3 = e2; e2 = e1; e1 = e0; d3 = d2; d2 = d1; d1 = d0;
            pv += WW;
        }
    } else {
        int gr = r0 - 15;
#pragma unroll 2
        for (int kk = 3; kk < 37; kk++) {
            float e0 = cE[kk], d0 = cC[kk];
            float v0 = 0.f, v1 = 0.f, v2 = 0.f, v3 = 0.f;
            if ((unsigned)gr < (unsigned)HH) {
                v0 = pv[0]; v1 = pv[PL]; v2 = pv[2 * PL]; v3 = pv[3 * PL];
            }
            VACC(e0, d0, 0) VACC(e1, d1, 1) VACC(e2, d2, 2) VACC(e3, d3, 3)
            e3 = e2; e2 = e1; e1 = e0; d3 = d2; d2 = d1; d1 = d0;
            pv += WW; gr++;
        }
    }
    // epilogue kk = 37..39 (e1=cE[36], e2=cE[35], e3=cE[34]; no rotation)
#pragma unroll
    for (int kk = 37; kk < 40; kk++) {
        int gr = r0 - 18 + kk;                        // >= 19, may exceed 511
        float v0 = 0.f, v1 = 0.f, v2 = 0.f, v3 = 0.f;
        if (gr < HH) {
            size_t idx = (size_t)gr * WW + j;
            v0 = t0[idx]; v1 = t0[PL + idx]; v2 = t0[2 * PL + idx]; v3 = t0[3 * PL + idx];
        }
        if (kk == 37) { VACC(e1, d1, 1) VACC(e2, d2, 2) VACC(e3, d3, 3) }
        if (kk == 38) { VACC(e1, d1, 2) VACC(e2, d2, 3) }
        if (kk == 39) { VACC(e1, d1, 3) }
    }
#pragma unroll
    for (int i = 0; i < 4; i++) {
        int h = r0 + i;
        float Hf = atanf(El[i] / (Ell[i] + EPSF));
        float S = logf((El[i] * El[i] + Ell[i] * Ell[i]) / (E[i] * E[i] + EPSF) + EPSF);
        float rx = Ex[i] / (E[i] + EPSF), ry = Ey[i] / (E[i] + EPSF);
        float Wv = atanf(rx * rx + ry * ry);
        size_t base = (size_t)(b * 6) * PIX + (size_t)h * WW + j;
        out[base] = Hf;
        out[base + PIX] = S;
        out[base + 5 * (size_t)PIX] = Wv;
    }
}
#undef VACC

extern "C" void kernel_launch(void* const* d_in, const int* in_sizes, int n_in,
                              void* d_out, int out_size, void* d_ws, size_t ws_size,
                              hipStream_t stream) {
    const float* batch = (const float*)d_in[0];
    const float* gcm   = (const float*)d_in[1];
    const float* w1    = (const float*)d_in[2];
    const float* b1    = (const float*)d_in[3];
    const float* w2    = (const float*)d_in[4];
    const float* b2    = (const float*)d_in[5];
    const float* w3    = (const float*)d_in[6];
    const float* b3    = (const float*)d_in[7];
    float* out = (float*)d_out;

    if (ws_size < WS_NEEDED) return;

    float* wsf = (float*)d_ws;
    float* tpl = (float*)((char*)d_ws + OFF_TPB);
    float* ehat = wsf + OFF_EH;
    float* chat = wsf + OFF_CH;

    prep_kernel<<<dim3(1), dim3(256), 0, stream>>>(w1, w2, wsf);
    conv12_kernel<<<dim3(8, 64, 8), dim3(256), 0, stream>>>(
        batch, (const unsigned short*)(wsf + OFF_W1R), b1,
        (const unsigned short*)(wsf + OFF_WR), b2, wsf, out);
    filter_kernel<<<dim3(8), dim3(160), 0, stream>>>(w3, b3, wsf);
    horiz_kernel<<<dim3(256, 8), dim3(256), 0, stream>>>(batch, gcm, ehat, chat, tpl);
    vert_kernel<<<dim3(8, 32, 8), dim3(256), 0, stream>>>(tpl, ehat, chat, out);
}

// Round 8
// 229.513 us; speedup vs baseline: 1.1283x; 1.0154x over previous
//
#include <hip/hip_runtime.h>
#include <hip/hip_bf16.h>

constexpr int BN = 8, HH = 512, WW = 512;
constexpr int PIX = HH * WW;
constexpr float EPSF = 1e-4f;

__device__ __forceinline__ float b2f(__hip_bfloat16 x) { return __bfloat162float(x); }
__device__ __forceinline__ __hip_bfloat16 f2b(float x) { return __float2bfloat16(x); }
__device__ __forceinline__ unsigned short bfbits(float x) {
    union { __hip_bfloat16 b; unsigned short u; } cv; cv.b = f2b(x); return cv.u;
}
__device__ __forceinline__ float ubf(unsigned short u) {
    union { unsigned int i; float f; } c; c.i = ((unsigned int)u) << 16; return c.f;
}
// hardware packed f32->bf16 (RNE): D = {hi:cvt(S1), lo:cvt(S0)}
__device__ __forceinline__ unsigned int cvtpk(float lo, float hi) {
    unsigned int r;
    asm("v_cvt_pk_bf16_f32 %0, %1, %2" : "=v"(r) : "v"(lo), "v"(hi));
    return r;
}
// silu via hw rcp (h is bf16-quantized downstream; ~2^-22 rel err invisible)
__device__ __forceinline__ float silu(float a) {
    return a * __builtin_amdgcn_rcpf(1.f + __expf(-a));
}

typedef __attribute__((ext_vector_type(8))) short bf16x8;   // MFMA A/B frag (4 VGPRs)
typedef __attribute__((ext_vector_type(4))) float f32x4;    // MFMA C/D frag

#define MF(acc, A, B) (acc) = __builtin_amdgcn_mfma_f32_16x16x32_bf16((A), (B), (acc), 0, 0, 0)

// load B-frag: 8 consecutive u16 (rows q*8..q*8+7) starting at off16 (must be 4-u16 aligned)
__device__ __forceinline__ bf16x8 ldb(const unsigned short* s, int off16) {
    const uint2* p = (const uint2*)(s + off16);
    uint2 a = p[0], c = p[1];
    union { uint4 u; bf16x8 v; } cv;
    cv.u = make_uint4(a.x, a.y, c.x, c.y);
    return cv.v;
}

// ---- workspace float offsets (small region) ----
constexpr int OFF_TOT = 0;       // 8*16 per-image channel totals (atomics)
constexpr int OFF_ROW0 = 128;
constexpr int OFF_ROW1 = 256;
constexpr int OFF_COL0 = 384;
constexpr int OFF_COL1 = 512;
constexpr int OFF_COR = 640;     // corners [b][hi][wi][16] -> 640..1151
constexpr int OFF_W1R = 1280;    // w1 A-frags hi(512 bf16)+lo(512 bf16) = 512 floats
constexpr int OFF_WR  = 2048;    // w2 A-frags hi(2560 bf16) + lo(2560 bf16)
constexpr int OFF_AFR = 8192;    // band A-frags: [b][10 frags][64 lanes] uint4 = 20480 floats
// ---- big buffers: tpl transposed [plane][b][j][h]; t0/t3 bf16, t1/t2 fp32 ----
constexpr size_t OFF_TP0 = 262144;                         // bytes
constexpr size_t SZ_TPH = (size_t)BN * PIX * 2;            // 4 MB (u16 plane)
constexpr size_t SZ_TPF = (size_t)BN * PIX * 4;            // 8 MB (f32 plane)
constexpr size_t OFF_TP1 = OFF_TP0 + SZ_TPH;
constexpr size_t OFF_TP2 = OFF_TP1 + SZ_TPF;
constexpr size_t OFF_TP3 = OFF_TP2 + SZ_TPF;
constexpr size_t WS_NEEDED = OFF_TP3 + SZ_TPH;             // ~25.4 MB

// ---------------- prep: zero atomic slots, swizzle w1/w2 into hi/lo A-fragments ----------------
__global__ void prep_kernel(const float* __restrict__ w1, const float* __restrict__ w2,
                            float* __restrict__ wsf) {
    int t = threadIdx.x;
    for (int i = t; i < 640; i += 256) wsf[i] = 0.f;
    unsigned short* ab = (unsigned short*)(wsf + OFF_WR);
    for (int idx = t; idx < 5120; idx += 256) {
        int part = idx / 2560;               // 0 = hi, 1 = lo
        int id = idx - part * 2560;
        int ks = id >> 9, rem = id & 511, lane = rem >> 3, j = id & 7;
        int oc = lane & 15, q = lane >> 4;
        int k = q * 8 + j;
        int tap = 2 * ks + (k >> 4), ic = k & 15;
        float val = (tap <= 8) ? w2[oc * 144 + ic * 9 + tap] : 0.f;
        float hv = b2f(f2b(val));
        ab[idx] = (part == 0) ? bfbits(val) : bfbits(val - hv);
    }
    unsigned short* a1 = (unsigned short*)(wsf + OFF_W1R);
    for (int idx = t; idx < 1024; idx += 256) {
        int part = idx >> 9;                 // 0 = hi, 1 = lo
        int id = idx & 511;
        int lane = id >> 3, j = id & 7;
        int oc = lane & 15, q = lane >> 4;
        int k = q * 8 + j;
        float val = (k < 27) ? w1[oc * 27 + k] : 0.f;
        float hv = b2f(f2b(val));
        a1[idx] = (part == 0) ? bfbits(val) : bfbits(val - hv);
    }
}

// ---------------- fused conv1(MFMA)+conv2(MFMA)+RGB with conv3-mean reduction ----------------
// (round-6 winner, unchanged)
__global__ __launch_bounds__(256) void conv12_kernel(const float* __restrict__ batch,
                                                     const unsigned short* __restrict__ w1buf,
                                                     const float* __restrict__ b1,
                                                     const unsigned short* __restrict__ abuf,
                                                     const float* __restrict__ b2v,
                                                     float* __restrict__ wsf,
                                                     float* __restrict__ out) {
    __shared__ unsigned short stb[3][12][68];
    __shared__ uint4 h1s[10 * 66 * 2];
    __shared__ float part[4][16];

    int tx = threadIdx.x;
    int lane = tx & 63, wave = tx >> 6;
    int n = lane & 15, q = lane >> 4;
    int w0 = blockIdx.x * 64, h0 = blockIdx.y * 8, b = blockIdx.z;

    union { uint4 u; bf16x8 v; } cv;
    const float* pb = batch + (size_t)(b * 3) * PIX;

    unsigned int* stw = (unsigned int*)&stb[0][0][0];
    for (int i = tx; i < 1224; i += 256) {
        int ch = i / 408, rem = i - ch * 408;
        int r = rem / 34, c2 = rem - r * 34;
        int gh = h0 - 2 + r, gw = w0 - 2 + 2 * c2;
        const float* p = pb + (size_t)ch * PIX + (size_t)gh * WW;
        bool rok = (gh >= 0) && (gh < HH);
        float v0 = (rok && gw >= 0 && gw < WW) ? p[gw] : 0.f;
        float v1 = (rok && gw + 1 >= 0 && gw + 1 < WW) ? p[gw + 1] : 0.f;
        stw[i] = cvtpk(v0, v1);
    }

    bf16x8 w1h, w1l;
    const uint4* w14 = (const uint4*)w1buf;
    cv.u = w14[lane];      w1h = cv.v;
    cv.u = w14[64 + lane]; w1l = cv.v;
    int koff[8];
#pragma unroll
    for (int j = 0; j < 8; j++) {
        int k = q * 8 + j;
        int kk = (k < 27) ? k : 0;
        int ic = kk / 9, rem = kk - ic * 9, kh = rem / 3, kw = rem - kh * 3;
        koff[j] = ic * 816 + kh * 68 + kw;
    }
    float b1q[4];
#pragma unroll
    for (int r = 0; r < 4; r++) b1q[r] = b1[q * 4 + r];
    bool hiq = (q == 3);
    __syncthreads();

    const unsigned short* sptr = &stb[0][0][0];
    unsigned int* hw = (unsigned int*)h1s;
    int i_c = wave * 16 + n;
    int r_c = (unsigned)i_c / 66u; int c_c = i_c - r_c * 66;
    int base_c = r_c * 68 + c_c;
    unsigned short x0 = sptr[base_c + koff[0]], x1 = sptr[base_c + koff[1]];
    unsigned short x2 = sptr[base_c + koff[2]], x3 = sptr[base_c + koff[3]];
    unsigned short x4 = sptr[base_c + koff[4]], x5 = sptr[base_c + koff[5]];
    unsigned short x6 = sptr[base_c + koff[6]], x7 = sptr[base_c + koff[7]];
    int g = wave;
    for (int gi = 0; gi < 11; gi++) {
        unsigned short y0 = 0, y1 = 0, y2 = 0, y3 = 0, y4 = 0, y5 = 0, y6 = 0, y7 = 0;
        int i_n = 0, c_n = 0;
        if (gi < 10) {
            i_n = (g + 4) * 16 + n; if (i_n > 659) i_n = 659;
            int r_n = (unsigned)i_n / 66u; c_n = i_n - r_n * 66;
            int base_n = r_n * 68 + c_n;
            y0 = sptr[base_n + koff[0]]; y1 = sptr[base_n + koff[1]];
            y2 = sptr[base_n + koff[2]]; y3 = sptr[base_n + koff[3]];
            y4 = sptr[base_n + koff[4]]; y5 = sptr[base_n + koff[5]];
            y6 = sptr[base_n + koff[6]]; y7 = sptr[base_n + koff[7]];
        }
        union { unsigned int w[4]; bf16x8 v; } bb;
        bb.w[0] = (unsigned int)x0 | ((unsigned int)x1 << 16);
        bb.w[1] = (unsigned int)x2 | ((unsigned int)x3 << 16);
        bb.w[2] = (unsigned int)x4 | ((unsigned int)x5 << 16);
        bb.w[3] = (unsigned int)x6 | ((unsigned int)x7 << 16);
        if (hiq) {
            bb.w[1] &= 0xFFFFu; bb.w[2] = 0u; bb.w[3] = 0u;
        }
        f32x4 a = {0, 0, 0, 0};
        MF(a, w1h, bb.v);
        MF(a, w1l, bb.v);
        int rr_ = (unsigned)i_c / 66u;
        int gh = h0 - 1 + rr_, gw = w0 - 1 + c_c;
        bool ok = ((unsigned)gh < (unsigned)HH) && ((unsigned)gw < (unsigned)WW);
        unsigned int p0 = cvtpk(silu(a[0] + b1q[0]), silu(a[1] + b1q[1]));
        unsigned int p1 = cvtpk(silu(a[2] + b1q[2]), silu(a[3] + b1q[3]));
        p0 = ok ? p0 : 0u;
        p1 = ok ? p1 : 0u;
        int swz = (c_c >> 2) & 1;
        int slot = i_c * 2 + ((q >= 2) ? (swz ^ 1) : swz);
        *(uint2*)&hw[slot * 4 + (q & 1) * 2] = make_uint2(p0, p1);
        x0 = y0; x1 = y1; x2 = y2; x3 = y3; x4 = y4; x5 = y5; x6 = y6; x7 = y7;
        i_c = i_n; c_c = c_n;
        g += 4;
    }

    for (int j = tx; j < 512; j += 256) {
        int rr = j >> 6, ccx = j & 63;
        size_t p = (size_t)(h0 + rr) * WW + (w0 + ccx);
        float v0 = pb[p], v1 = pb[(size_t)PIX + p], v2 = pb[2 * (size_t)PIX + p];
        int mx  = (v0 >= v1 && v0 >= v2) ? 0 : ((v1 >= v2) ? 1 : 2);
        int mx2 = (v2 >= v1 && v2 >= v0) ? 2 : ((v1 >= v0) ? 1 : 0);
        int mn  = (v0 <= v1 && v0 <= v2) ? 0 : ((v1 <= v2) ? 1 : 2);
        int mn2 = (v2 <= v1 && v2 <= v0) ? 2 : ((v1 <= v0) ? 1 : 0);
#pragma unroll
        for (int c = 0; c < 3; c++) {
            float r = 0.5f * ((float)(c == mx) + (float)(c == mx2))
                    - 0.5f * ((float)(c == mn) + (float)(c == mn2));
            out[(size_t)(b * 6 + 2 + c) * PIX + p] = r;
        }
    }
    __syncthreads();

    bf16x8 ah[5], al[5];
    const uint4* ab4 = (const uint4*)abuf;
#pragma unroll
    for (int ks = 0; ks < 5; ks++) {
        cv.u = ab4[ks * 64 + lane];       ah[ks] = cv.v;
        cv.u = ab4[320 + ks * 64 + lane]; al[ks] = cv.v;
    }
    float b2q[4];
#pragma unroll
    for (int r = 0; r < 4; r++) b2q[r] = b2v[q * 4 + r];

    float tt[4] = {0, 0, 0, 0};
    float cs0[4] = {0, 0, 0, 0};
    float cs1[4] = {0, 0, 0, 0};
    for (int rloc = 0; rloc < 2; rloc++) {
        int row = wave * 2 + rloc;
        int grow = h0 + row;
        f32x4 acc[4] = {{0,0,0,0},{0,0,0,0},{0,0,0,0},{0,0,0,0}};
#pragma unroll
        for (int ks = 0; ks < 5; ks++) {
            int tap = 2 * ks + (q >> 1); if (tap > 8) tap = 8;
            int dh = tap / 3 - 1, dw = tap % 3 - 1;
            int half = q & 1;
            int lr = row + 1 + dh;
#pragma unroll
            for (int t = 0; t < 4; t++) {
                int c = 1 + dw + t * 16 + n;
                cv.u = h1s[(lr * 66 + c) * 2 + (half ^ ((c >> 2) & 1))];
                MF(acc[t], ah[ks], cv.v);
                MF(acc[t], al[ks], cv.v);
            }
        }
        float sv[4][4];
#pragma unroll
        for (int t = 0; t < 4; t++)
#pragma unroll
            for (int r = 0; r < 4; r++)
                sv[t][r] = silu(acc[t][r] + b2q[r]);
#pragma unroll
        for (int r = 0; r < 4; r++) tt[r] += sv[0][r] + sv[1][r] + sv[2][r] + sv[3][r];
        if (grow == 0 || grow == HH - 1) {
            int off = (grow == 0) ? OFF_ROW0 : OFF_ROW1;
#pragma unroll
            for (int r = 0; r < 4; r++) {
                float x = sv[0][r] + sv[1][r] + sv[2][r] + sv[3][r];
#pragma unroll
                for (int d = 1; d < 16; d <<= 1) x += __shfl_xor(x, d, 64);
                if (n == 0) atomicAdd(&wsf[off + b * 16 + q * 4 + r], x);
            }
        }
        if (blockIdx.x == 0 && n == 0)
#pragma unroll
            for (int r = 0; r < 4; r++) cs0[r] += sv[0][r];
        if (blockIdx.x == 7 && n == 15)
#pragma unroll
            for (int r = 0; r < 4; r++) cs1[r] += sv[3][r];
        if ((grow == 0 || grow == HH - 1)) {
            int hi = (grow == 0) ? 0 : 1;
            if (blockIdx.x == 0 && n == 0)
#pragma unroll
                for (int r = 0; r < 4; r++)
                    wsf[OFF_COR + ((b * 2 + hi) * 2 + 0) * 16 + q * 4 + r] = sv[0][r];
            if (blockIdx.x == 7 && n == 15)
#pragma unroll
                for (int r = 0; r < 4; r++)
                    wsf[OFF_COR + ((b * 2 + hi) * 2 + 1) * 16 + q * 4 + r] = sv[3][r];
        }
    }
    if (blockIdx.x == 0 && n == 0)
#pragma unroll
        for (int r = 0; r < 4; r++) atomicAdd(&wsf[OFF_COL0 + b * 16 + q * 4 + r], cs0[r]);
    if (blockIdx.x == 7 && n == 15)
#pragma unroll
        for (int r = 0; r < 4; r++) atomicAdd(&wsf[OFF_COL1 + b * 16 + q * 4 + r], cs1[r]);
#pragma unroll
    for (int r = 0; r < 4; r++) {
        float x = tt[r];
#pragma unroll
        for (int d = 1; d < 16; d <<= 1) x += __shfl_xor(x, d, 64);
        tt[r] = x;
    }
    if (n == 0)
#pragma unroll
        for (int r = 0; r < 4; r++) part[wave][q * 4 + r] = tt[r];
    __syncthreads();
    if (tx < 16)
        atomicAdd(&wsf[OFF_TOT + b * 16 + tx],
                  part[0][tx] + part[1][tx] + part[2][tx] + part[3][tx]);
}

// ---------------- filter: mean via edge algebra, taps, and band-matrix A-fragments ----------------
// A[r][ki] = co[ki - r] for 0 <= ki-r <= 36 else 0 (ki = ks*32 + q*8 + j, r = lane&15).
// Frags: f 0..5 = Ae (ks0 h,m,l; ks1 h,m,l)  f 6..9 = Ac (ks0 h,m; ks1 h,m). Shared by
// horiz (band over cols) and vert (band over rows). 3-term split keeps El/Ell ~fp32:
// Hf = atan(El/(Ell+1e-4)) pi-flips if Ell error crosses the 1e-4 boundary.
__global__ void filter_kernel(const float* __restrict__ w3, const float* __restrict__ b3,
                              float* __restrict__ wsf) {
    int b = blockIdx.x, t = threadIdx.x;   // 160 threads
    __shared__ float red[160];
    float val = 0.f;
    if (t < 144) {
        int ic = t / 9, tap = t % 9, kh = tap / 3, kw = tap % 3;
        float T = wsf[OFF_TOT + b * 16 + ic];
        int hi = -1, wi = -1;
        if (kh == 0) { T -= wsf[OFF_ROW1 + b * 16 + ic]; hi = 1; }
        else if (kh == 2) { T -= wsf[OFF_ROW0 + b * 16 + ic]; hi = 0; }
        if (kw == 0) { T -= wsf[OFF_COL1 + b * 16 + ic]; wi = 1; }
        else if (kw == 2) { T -= wsf[OFF_COL0 + b * 16 + ic]; wi = 0; }
        if (hi >= 0 && wi >= 0) T += wsf[OFF_COR + ((b * 2 + hi) * 2 + wi) * 16 + ic];
        val = w3[t] * T;
    }
    red[t] = val;
    __syncthreads();
    __shared__ float sh_mean;
    if (t == 0) {
        float S = 0.f;
        for (int i = 0; i < 144; i++) S += red[i];
        sh_mean = b3[0] + S * (1.f / (float)PIX);
    }
    __syncthreads();
    float scale = fminf(2.5f, fmaxf(-2.5f, sh_mean));
    float sd = exp2f(scale);
    float fs = ceilf(3.f * sd + 0.5f);
    float e = 0.f, c = 0.f;
    if (t < 37) {
        float x = (float)(t - 18);
        if (fabsf(x) <= fs) {
            float qq = x / sd;
            e = __expf(-0.5f * qq * qq);
            c = -x / (sd * sd * sd * 6.28318530717958647692f) * e;
        }
    }
    __shared__ float sa[40], sb2[40];
    if (t < 37) { sa[t] = e; sb2[t] = fabsf(c); }
    __syncthreads();
    __shared__ float Se, Sc;
    if (t == 0) {
        float a = 0.f, d = 0.f;
        for (int i = 0; i < 37; i++) { a += sa[i]; d += sb2[i]; }
        Se = a; Sc = d;
    }
    __syncthreads();
    __shared__ float sEn[37], sCn[37];
    if (t < 37) { sEn[t] = e / Se; sCn[t] = c / Sc; }
    __syncthreads();
    if (t < 64) {
        int r = t & 15, q = t >> 4;
        uint4* afr = (uint4*)(wsf + OFF_AFR) + (size_t)b * 640 + t;
#pragma unroll
        for (int ks = 0; ks < 2; ks++) {
            unsigned short eh[8], em[8], el[8], chp[8], cmp[8];
#pragma unroll
            for (int j2 = 0; j2 < 8; j2++) {
                int d = ks * 32 + q * 8 + j2 - r;
                bool ok = (d >= 0) && (d <= 36);
                float ve = ok ? sEn[ok ? d : 0] : 0.f;
                float vc = ok ? sCn[ok ? d : 0] : 0.f;
                eh[j2] = bfbits(ve);
                float r1 = ve - ubf(eh[j2]);
                em[j2] = bfbits(r1);
                el[j2] = bfbits(r1 - ubf(em[j2]));
                chp[j2] = bfbits(vc);
                cmp[j2] = bfbits(vc - ubf(chp[j2]));
            }
#define PK2(a0, a1) ((unsigned)(a0) | ((unsigned)(a1) << 16))
            afr[(ks * 3 + 0) * 64] = make_uint4(PK2(eh[0], eh[1]), PK2(eh[2], eh[3]), PK2(eh[4], eh[5]), PK2(eh[6], eh[7]));
            afr[(ks * 3 + 1) * 64] = make_uint4(PK2(em[0], em[1]), PK2(em[2], em[3]), PK2(em[4], em[5]), PK2(em[6], em[7]));
            afr[(ks * 3 + 2) * 64] = make_uint4(PK2(el[0], el[1]), PK2(el[2], el[3]), PK2(el[4], el[5]), PK2(el[6], el[7]));
            afr[(6 + ks * 2 + 0) * 64] = make_uint4(PK2(chp[0], chp[1]), PK2(chp[2], chp[3]), PK2(chp[4], chp[5]), PK2(chp[6], chp[7]));
            afr[(6 + ks * 2 + 1) * 64] = make_uint4(PK2(cmp[0], cmp[1]), PK2(cmp[2], cmp[3]), PK2(cmp[4], cmp[5]), PK2(cmp[6], cmp[7]));
#undef PK2
        }
    }
}

// ---------------- horizontal pass (MFMA): batch -> xg -> t0..t3, tpl transposed [j][h] ----------------
// Block 256 thr: out 32 j x 32 h. Staged xg: 7 part-planes (x0; x1 h,m,l; x2 h,m,l),
// 32 h x 80 cols (j0-18..j0+61), row-pad 84. Wave w: jt=w&1, ht=w>>1.
__global__ __launch_bounds__(256) void horiz_kernel(const float* __restrict__ batch,
                                                    const float* __restrict__ gcm,
                                                    const float* __restrict__ wsf,
                                                    unsigned short* __restrict__ tp0,
                                                    float* __restrict__ tp1,
                                                    float* __restrict__ tp2,
                                                    unsigned short* __restrict__ tp3) {
    __shared__ unsigned short sx[7 * 32 * 84];   // 37,632 B
    int tx = threadIdx.x;
    int lane = tx & 63, wave = tx >> 6;
    int n = lane & 15, q = lane >> 4;
    int j0 = blockIdx.x * 32, h0 = blockIdx.y * 32, b = blockIdx.z;
    const float* pb = batch + (size_t)(b * 3) * PIX;
    float g0 = gcm[0], g1 = gcm[1], g2 = gcm[2];
    float g3 = gcm[3], g4 = gcm[4], g5 = gcm[5];
    float g6 = gcm[6], g7 = gcm[7], g8 = gcm[8];
    for (int i = tx; i < 2560; i += 256) {
        int hh = i / 80, sc = i - hh * 80;
        int gc = j0 - 18 + sc;
        float v0 = 0.f, v1 = 0.f, v2 = 0.f;
        if ((unsigned)gc < (unsigned)WW) {
            size_t p = (size_t)(h0 + hh) * WW + gc;
            v0 = pb[p]; v1 = pb[(size_t)PIX + p]; v2 = pb[2 * (size_t)PIX + p];
        }
        float x0 = g0 * v0 + g1 * v1 + g2 * v2;
        float x1 = g3 * v0 + g4 * v1 + g5 * v2;
        float x2 = g6 * v0 + g7 * v1 + g8 * v2;
        int o = hh * 84 + sc;
        sx[o] = bfbits(x0);
        unsigned short h1 = bfbits(x1); sx[2688 + o] = h1;
        float r1 = x1 - ubf(h1); unsigned short m1 = bfbits(r1); sx[2 * 2688 + o] = m1;
        sx[3 * 2688 + o] = bfbits(r1 - ubf(m1));
        unsigned short h2 = bfbits(x2); sx[4 * 2688 + o] = h2;
        float r2 = x2 - ubf(h2); unsigned short m2 = bfbits(r2); sx[5 * 2688 + o] = m2;
        sx[6 * 2688 + o] = bfbits(r2 - ubf(m2));
    }
    const uint4* afr = (const uint4*)(wsf + OFF_AFR) + (size_t)b * 640 + lane;
    union { uint4 u; bf16x8 v; } cv;
    bf16x8 Ae[2][3], Ac[2][2];
#pragma unroll
    for (int ks = 0; ks < 2; ks++) {
#pragma unroll
        for (int p = 0; p < 3; p++) { cv.u = afr[(ks * 3 + p) * 64]; Ae[ks][p] = cv.v; }
#pragma unroll
        for (int p = 0; p < 2; p++) { cv.u = afr[(6 + ks * 2 + p) * 64]; Ac[ks][p] = cv.v; }
    }
    __syncthreads();
    int jt = wave & 1, ht = wave >> 1;
    f32x4 a0 = {0,0,0,0}, a1 = {0,0,0,0}, a2 = {0,0,0,0}, a3 = {0,0,0,0};
    int rb = (ht * 16 + n) * 84 + jt * 16 + q * 8;
#pragma unroll
    for (int ks = 0; ks < 2; ks++) {
        int rk = rb + ks * 32;
        bf16x8 B0  = ldb(sx, rk);
        bf16x8 B1h = ldb(sx, 2688 + rk), B1m = ldb(sx, 2 * 2688 + rk), B1l = ldb(sx, 3 * 2688 + rk);
        bf16x8 B2h = ldb(sx, 4 * 2688 + rk), B2m = ldb(sx, 5 * 2688 + rk), B2l = ldb(sx, 6 * 2688 + rk);
        MF(a0, Ae[ks][0], B0); MF(a0, Ae[ks][1], B0);
        MF(a3, Ac[ks][0], B0); MF(a3, Ac[ks][1], B0);
        MF(a1, Ae[ks][0], B1h); MF(a1, Ae[ks][0], B1m); MF(a1, Ae[ks][1], B1h);
        MF(a1, Ae[ks][0], B1l); MF(a1, Ae[ks][2], B1h); MF(a1, Ae[ks][1], B1m);
        MF(a2, Ae[ks][0], B2h); MF(a2, Ae[ks][0], B2m); MF(a2, Ae[ks][1], B2h);
        MF(a2, Ae[ks][0], B2l); MF(a2, Ae[ks][2], B2h); MF(a2, Ae[ks][1], B2m);
    }
    int jo = j0 + jt * 16 + q * 4;
    int ho = h0 + ht * 16 + n;
#pragma unroll
    for (int r = 0; r < 4; r++) {
        size_t ix = ((size_t)b * 512 + (jo + r)) * 512 + ho;
        tp0[ix] = bfbits(a0[r]);
        tp1[ix] = a1[r];
        tp2[ix] = a2[r];
        tp3[ix] = bfbits(a3[r]);
    }
}

// ---------------- vertical pass (MFMA) + final math -> out ch0,1,5 ----------------
// Block 256 thr: out 32 h x 32 j. Staged: 8 part-planes (t0; t1 h,m,l; t2 h,m,l; t3),
// 32 j x 80 rows (r0-18..r0+61), pad 84. Wave w: ct=w&1, rt=w>>1.
__global__ __launch_bounds__(256) void vert_kernel(const float* __restrict__ wsf,
                                                   const unsigned short* __restrict__ tp0,
                                                   const float* __restrict__ tp1,
                                                   const float* __restrict__ tp2,
                                                   const unsigned short* __restrict__ tp3,
                                                   float* __restrict__ out) {
    __shared__ unsigned short sb[8 * 32 * 84];   // 43,008 B
    int tx = threadIdx.x;
    int lane = tx & 63, wave = tx >> 6;
    int n = lane & 15, q = lane >> 4;
    int j0 = blockIdx.x * 32, r0 = blockIdx.y * 32, b = blockIdx.z;
    for (int i = tx; i < 2560; i += 256) {
        int jj = i / 80, sr = i - jj * 80;
        int gh = r0 - 18 + sr;
        unsigned short w0 = 0, w7 = 0; float f1 = 0.f, f2 = 0.f;
        if ((unsigned)gh < (unsigned)HH) {
            size_t ix = ((size_t)b * 512 + (j0 + jj)) * 512 + gh;
            w0 = tp0[ix]; f1 = tp1[ix]; f2 = tp2[ix]; w7 = tp3[ix];
        }
        int o = jj * 84 + sr;
        sb[o] = w0;
        unsigned short h1 = bfbits(f1); sb[2688 + o] = h1;
        float r1 = f1 - ubf(h1); unsigned short m1 = bfbits(r1); sb[2 * 2688 + o] = m1;
        sb[3 * 2688 + o] = bfbits(r1 - ubf(m1));
        unsigned short h2 = bfbits(f2); sb[4 * 2688 + o] = h2;
        float r2 = f2 - ubf(h2); unsigned short m2 = bfbits(r2); sb[5 * 2688 + o] = m2;
        sb[6 * 2688 + o] = bfbits(r2 - ubf(m2));
        sb[7 * 2688 + o] = w7;
    }
    const uint4* afr = (const uint4*)(wsf + OFF_AFR) + (size_t)b * 640 + lane;
    union { uint4 u; bf16x8 v; } cv;
    bf16x8 Ae[2][3], Ac[2][2];
#pragma unroll
    for (int ks = 0; ks < 2; ks++) {
#pragma unroll
        for (int p = 0; p < 3; p++) { cv.u = afr[(ks * 3 + p) * 64]; Ae[ks][p] = cv.v; }
#pragma unroll
        for (int p = 0; p < 2; p++) { cv.u = afr[(6 + ks * 2 + p) * 64]; Ac[ks][p] = cv.v; }
    }
    __syncthreads();
    int ct = wave & 1, rt = wave >> 1;
    f32x4 aE = {0,0,0,0}, aX = {0,0,0,0}, aY = {0,0,0,0}, aL = {0,0,0,0}, aLL = {0,0,0,0};
    int rb = (ct * 16 + n) * 84 + rt * 16 + q * 8;
#pragma unroll
    for (int ks = 0; ks < 2; ks++) {
        int rk = rb + ks * 32;
        bf16x8 B0  = ldb(sb, rk);
        bf16x8 B1h = ldb(sb, 2688 + rk), B1m = ldb(sb, 2 * 2688 + rk), B1l = ldb(sb, 3 * 2688 + rk);
        bf16x8 B2h = ldb(sb, 4 * 2688 + rk), B2m = ldb(sb, 5 * 2688 + rk), B2l = ldb(sb, 6 * 2688 + rk);
        bf16x8 B3  = ldb(sb, 7 * 2688 + rk);
        MF(aE, Ae[ks][0], B0); MF(aE, Ae[ks][1], B0);
        MF(aX, Ac[ks][0], B0); MF(aX, Ac[ks][1], B0);
        MF(aY, Ae[ks][0], B3); MF(aY, Ae[ks][1], B3);
        MF(aL, Ae[ks][0], B1h); MF(aL, Ae[ks][0], B1m); MF(aL, Ae[ks][1], B1h);
        MF(aL, Ae[ks][0], B1l); MF(aL, Ae[ks][2], B1h); MF(aL, Ae[ks][1], B1m);
        MF(aLL, Ae[ks][0], B2h); MF(aLL, Ae[ks][0], B2m); MF(aLL, Ae[ks][1], B2h);
        MF(aLL, Ae[ks][0], B2l); MF(aLL, Ae[ks][2], B2h); MF(aLL, Ae[ks][1], B2m);
    }
    int ho = r0 + rt * 16 + q * 4;
    int jo = j0 + ct * 16 + n;
#pragma unroll
    for (int r = 0; r < 4; r++) {
        float E = aE[r], Ex = aX[r], Ey = aY[r], El = aL[r], Ell = aLL[r];
        float Hf = atanf(El / (Ell + EPSF));
        float S = logf((El * El + Ell * Ell) / (E * E + EPSF) + EPSF);
        float rx = Ex / (E + EPSF), ry = Ey / (E + EPSF);
        float Wv = atanf(rx * rx + ry * ry);
        size_t base = (size_t)(b * 6) * PIX + (size_t)(ho + r) * WW + jo;
        out[base] = Hf;
        out[base + PIX] = S;
        out[base + 5 * (size_t)PIX] = Wv;
    }
}

extern "C" void kernel_launch(void* const* d_in, const int* in_sizes, int n_in,
                              void* d_out, int out_size, void* d_ws, size_t ws_size,
                              hipStream_t stream) {
    const float* batch = (const float*)d_in[0];
    const float* gcm   = (const float*)d_in[1];
    const float* w1    = (const float*)d_in[2];
    const float* b1    = (const float*)d_in[3];
    const float* w2    = (const float*)d_in[4];
    const float* b2    = (const float*)d_in[5];
    const float* w3    = (const float*)d_in[6];
    const float* b3    = (const float*)d_in[7];
    float* out = (float*)d_out;

    if (ws_size < WS_NEEDED) return;

    float* wsf = (float*)d_ws;
    unsigned short* tp0 = (unsigned short*)((char*)d_ws + OFF_TP0);
    float* tp1 = (float*)((char*)d_ws + OFF_TP1);
    float* tp2 = (float*)((char*)d_ws + OFF_TP2);
    unsigned short* tp3 = (unsigned short*)((char*)d_ws + OFF_TP3);

    prep_kernel<<<dim3(1), dim3(256), 0, stream>>>(w1, w2, wsf);
    conv12_kernel<<<dim3(8, 64, 8), dim3(256), 0, stream>>>(
        batch, (const unsigned short*)(wsf + OFF_W1R), b1,
        (const unsigned short*)(wsf + OFF_WR), b2, wsf, out);
    filter_kernel<<<dim3(8), dim3(160), 0, stream>>>(w3, b3, wsf);
    horiz_kernel<<<dim3(16, 16, 8), dim3(256), 0, stream>>>(batch, gcm, wsf, tp0, tp1, tp2, tp3);
    vert_kernel<<<dim3(16, 16, 8), dim3(256), 0, stream>>>(wsf, tp0, tp1, tp2, tp3, out);
}

// Round 9
// 224.937 us; speedup vs baseline: 1.1513x; 1.0203x over previous
//
#include <hip/hip_runtime.h>
#include <hip/hip_bf16.h>

constexpr int BN = 8, HH = 512, WW = 512;
constexpr int PIX = HH * WW;
constexpr float EPSF = 1e-4f;

__device__ __forceinline__ float b2f(__hip_bfloat16 x) { return __bfloat162float(x); }
__device__ __forceinline__ __hip_bfloat16 f2b(float x) { return __float2bfloat16(x); }
__device__ __forceinline__ unsigned short bfbits(float x) {
    union { __hip_bfloat16 b; unsigned short u; } cv; cv.b = f2b(x); return cv.u;
}
__device__ __forceinline__ float ubf(unsigned short u) {
    union { unsigned int i; float f; } c; c.i = ((unsigned int)u) << 16; return c.f;
}
// hardware packed f32->bf16 (RNE): D = {hi:cvt(S1), lo:cvt(S0)}
__device__ __forceinline__ unsigned int cvtpk(float lo, float hi) {
    unsigned int r;
    asm("v_cvt_pk_bf16_f32 %0, %1, %2" : "=v"(r) : "v"(lo), "v"(hi));
    return r;
}
// silu via hw rcp (h is bf16-quantized downstream; ~2^-22 rel err invisible)
__device__ __forceinline__ float silu(float a) {
    return a * __builtin_amdgcn_rcpf(1.f + __expf(-a));
}

typedef __attribute__((ext_vector_type(8))) short bf16x8;   // MFMA A/B frag (4 VGPRs)
typedef __attribute__((ext_vector_type(4))) float f32x4;    // MFMA C/D frag

#define MF(acc, A, B) (acc) = __builtin_amdgcn_mfma_f32_16x16x32_bf16((A), (B), (acc), 0, 0, 0)

// load B-frag: 8 consecutive u16 (rows q*8..q*8+7) starting at off16 (must be 4-u16 aligned)
__device__ __forceinline__ bf16x8 ldb(const unsigned short* s, int off16) {
    const uint2* p = (const uint2*)(s + off16);
    uint2 a = p[0], c = p[1];
    union { uint4 u; bf16x8 v; } cv;
    cv.u = make_uint4(a.x, a.y, c.x, c.y);
    return cv.v;
}

// ---- workspace float offsets (small region) ----
constexpr int OFF_TOT = 0;       // 8*16 per-image channel totals (atomics)
constexpr int OFF_ROW0 = 128;
constexpr int OFF_ROW1 = 256;
constexpr int OFF_COL0 = 384;
constexpr int OFF_COL1 = 512;
constexpr int OFF_COR = 640;     // corners [b][hi][wi][16] -> 640..1151
constexpr int OFF_W1R = 1280;    // w1 A-frags hi(512 bf16)+lo(512 bf16) = 512 floats
constexpr int OFF_WR  = 2048;    // w2 A-frags hi(2560 bf16) + lo(2560 bf16)
constexpr int OFF_AFR = 8192;    // band A-frags: [b][10 frags][64 lanes] uint4 = 20480 floats
// ---- big buffers: tpl transposed [plane][b][j][h]; t0/t3 bf16, t1/t2 fp32 ----
constexpr size_t OFF_TP0 = 262144;                         // bytes
constexpr size_t SZ_TPH = (size_t)BN * PIX * 2;            // 4 MB (u16 plane)
constexpr size_t SZ_TPF = (size_t)BN * PIX * 4;            // 8 MB (f32 plane)
constexpr size_t OFF_TP1 = OFF_TP0 + SZ_TPH;
constexpr size_t OFF_TP2 = OFF_TP1 + SZ_TPF;
constexpr size_t OFF_TP3 = OFF_TP2 + SZ_TPF;
constexpr size_t WS_NEEDED = OFF_TP3 + SZ_TPH;             // ~25.4 MB

// ---------------- prep: zero atomic slots, swizzle w1/w2 into hi/lo A-fragments ----------------
__global__ void prep_kernel(const float* __restrict__ w1, const float* __restrict__ w2,
                            float* __restrict__ wsf) {
    int t = threadIdx.x;
    for (int i = t; i < 640; i += 256) wsf[i] = 0.f;
    unsigned short* ab = (unsigned short*)(wsf + OFF_WR);
    for (int idx = t; idx < 5120; idx += 256) {
        int part = idx / 2560;               // 0 = hi, 1 = lo
        int id = idx - part * 2560;
        int ks = id >> 9, rem = id & 511, lane = rem >> 3, j = id & 7;
        int oc = lane & 15, q = lane >> 4;
        int k = q * 8 + j;
        int tap = 2 * ks + (k >> 4), ic = k & 15;
        float val = (tap <= 8) ? w2[oc * 144 + ic * 9 + tap] : 0.f;
        float hv = b2f(f2b(val));
        ab[idx] = (part == 0) ? bfbits(val) : bfbits(val - hv);
    }
    unsigned short* a1 = (unsigned short*)(wsf + OFF_W1R);
    for (int idx = t; idx < 1024; idx += 256) {
        int part = idx >> 9;                 // 0 = hi, 1 = lo
        int id = idx & 511;
        int lane = id >> 3, j = id & 7;
        int oc = lane & 15, q = lane >> 4;
        int k = q * 8 + j;
        float val = (k < 27) ? w1[oc * 27 + k] : 0.f;
        float hv = b2f(f2b(val));
        a1[idx] = (part == 0) ? bfbits(val) : bfbits(val - hv);
    }
}

// ---------------- fused conv1(MFMA)+conv2(MFMA)+RGB with conv3-mean reduction ----------------
// (round-6 winner, unchanged -- CONTROL for this round)
__global__ __launch_bounds__(256) void conv12_kernel(const float* __restrict__ batch,
                                                     const unsigned short* __restrict__ w1buf,
                                                     const float* __restrict__ b1,
                                                     const unsigned short* __restrict__ abuf,
                                                     const float* __restrict__ b2v,
                                                     float* __restrict__ wsf,
                                                     float* __restrict__ out) {
    __shared__ unsigned short stb[3][12][68];
    __shared__ uint4 h1s[10 * 66 * 2];
    __shared__ float part[4][16];

    int tx = threadIdx.x;
    int lane = tx & 63, wave = tx >> 6;
    int n = lane & 15, q = lane >> 4;
    int w0 = blockIdx.x * 64, h0 = blockIdx.y * 8, b = blockIdx.z;

    union { uint4 u; bf16x8 v; } cv;
    const float* pb = batch + (size_t)(b * 3) * PIX;

    unsigned int* stw = (unsigned int*)&stb[0][0][0];
    for (int i = tx; i < 1224; i += 256) {
        int ch = i / 408, rem = i - ch * 408;
        int r = rem / 34, c2 = rem - r * 34;
        int gh = h0 - 2 + r, gw = w0 - 2 + 2 * c2;
        const float* p = pb + (size_t)ch * PIX + (size_t)gh * WW;
        bool rok = (gh >= 0) && (gh < HH);
        float v0 = (rok && gw >= 0 && gw < WW) ? p[gw] : 0.f;
        float v1 = (rok && gw + 1 >= 0 && gw + 1 < WW) ? p[gw + 1] : 0.f;
        stw[i] = cvtpk(v0, v1);
    }

    bf16x8 w1h, w1l;
    const uint4* w14 = (const uint4*)w1buf;
    cv.u = w14[lane];      w1h = cv.v;
    cv.u = w14[64 + lane]; w1l = cv.v;
    int koff[8];
#pragma unroll
    for (int j = 0; j < 8; j++) {
        int k = q * 8 + j;
        int kk = (k < 27) ? k : 0;
        int ic = kk / 9, rem = kk - ic * 9, kh = rem / 3, kw = rem - kh * 3;
        koff[j] = ic * 816 + kh * 68 + kw;
    }
    float b1q[4];
#pragma unroll
    for (int r = 0; r < 4; r++) b1q[r] = b1[q * 4 + r];
    bool hiq = (q == 3);
    __syncthreads();

    const unsigned short* sptr = &stb[0][0][0];
    unsigned int* hw = (unsigned int*)h1s;
    int i_c = wave * 16 + n;
    int r_c = (unsigned)i_c / 66u; int c_c = i_c - r_c * 66;
    int base_c = r_c * 68 + c_c;
    unsigned short x0 = sptr[base_c + koff[0]], x1 = sptr[base_c + koff[1]];
    unsigned short x2 = sptr[base_c + koff[2]], x3 = sptr[base_c + koff[3]];
    unsigned short x4 = sptr[base_c + koff[4]], x5 = sptr[base_c + koff[5]];
    unsigned short x6 = sptr[base_c + koff[6]], x7 = sptr[base_c + koff[7]];
    int g = wave;
    for (int gi = 0; gi < 11; gi++) {
        unsigned short y0 = 0, y1 = 0, y2 = 0, y3 = 0, y4 = 0, y5 = 0, y6 = 0, y7 = 0;
        int i_n = 0, c_n = 0;
        if (gi < 10) {
            i_n = (g + 4) * 16 + n; if (i_n > 659) i_n = 659;
            int r_n = (unsigned)i_n / 66u; c_n = i_n - r_n * 66;
            int base_n = r_n * 68 + c_n;
            y0 = sptr[base_n + koff[0]]; y1 = sptr[base_n + koff[1]];
            y2 = sptr[base_n + koff[2]]; y3 = sptr[base_n + koff[3]];
            y4 = sptr[base_n + koff[4]]; y5 = sptr[base_n + koff[5]];
            y6 = sptr[base_n + koff[6]]; y7 = sptr[base_n + koff[7]];
        }
        union { unsigned int w[4]; bf16x8 v; } bb;
        bb.w[0] = (unsigned int)x0 | ((unsigned int)x1 << 16);
        bb.w[1] = (unsigned int)x2 | ((unsigned int)x3 << 16);
        bb.w[2] = (unsigned int)x4 | ((unsigned int)x5 << 16);
        bb.w[3] = (unsigned int)x6 | ((unsigned int)x7 << 16);
        if (hiq) {
            bb.w[1] &= 0xFFFFu; bb.w[2] = 0u; bb.w[3] = 0u;
        }
        f32x4 a = {0, 0, 0, 0};
        MF(a, w1h, bb.v);
        MF(a, w1l, bb.v);
        int rr_ = (unsigned)i_c / 66u;
        int gh = h0 - 1 + rr_, gw = w0 - 1 + c_c;
        bool ok = ((unsigned)gh < (unsigned)HH) && ((unsigned)gw < (unsigned)WW);
        unsigned int p0 = cvtpk(silu(a[0] + b1q[0]), silu(a[1] + b1q[1]));
        unsigned int p1 = cvtpk(silu(a[2] + b1q[2]), silu(a[3] + b1q[3]));
        p0 = ok ? p0 : 0u;
        p1 = ok ? p1 : 0u;
        int swz = (c_c >> 2) & 1;
        int slot = i_c * 2 + ((q >= 2) ? (swz ^ 1) : swz);
        *(uint2*)&hw[slot * 4 + (q & 1) * 2] = make_uint2(p0, p1);
        x0 = y0; x1 = y1; x2 = y2; x3 = y3; x4 = y4; x5 = y5; x6 = y6; x7 = y7;
        i_c = i_n; c_c = c_n;
        g += 4;
    }

    for (int j = tx; j < 512; j += 256) {
        int rr = j >> 6, ccx = j & 63;
        size_t p = (size_t)(h0 + rr) * WW + (w0 + ccx);
        float v0 = pb[p], v1 = pb[(size_t)PIX + p], v2 = pb[2 * (size_t)PIX + p];
        int mx  = (v0 >= v1 && v0 >= v2) ? 0 : ((v1 >= v2) ? 1 : 2);
        int mx2 = (v2 >= v1 && v2 >= v0) ? 2 : ((v1 >= v0) ? 1 : 0);
        int mn  = (v0 <= v1 && v0 <= v2) ? 0 : ((v1 <= v2) ? 1 : 2);
        int mn2 = (v2 <= v1 && v2 <= v0) ? 2 : ((v1 <= v0) ? 1 : 0);
#pragma unroll
        for (int c = 0; c < 3; c++) {
            float r = 0.5f * ((float)(c == mx) + (float)(c == mx2))
                    - 0.5f * ((float)(c == mn) + (float)(c == mn2));
            out[(size_t)(b * 6 + 2 + c) * PIX + p] = r;
        }
    }
    __syncthreads();

    bf16x8 ah[5], al[5];
    const uint4* ab4 = (const uint4*)abuf;
#pragma unroll
    for (int ks = 0; ks < 5; ks++) {
        cv.u = ab4[ks * 64 + lane];       ah[ks] = cv.v;
        cv.u = ab4[320 + ks * 64 + lane]; al[ks] = cv.v;
    }
    float b2q[4];
#pragma unroll
    for (int r = 0; r < 4; r++) b2q[r] = b2v[q * 4 + r];

    float tt[4] = {0, 0, 0, 0};
    float cs0[4] = {0, 0, 0, 0};
    float cs1[4] = {0, 0, 0, 0};
    for (int rloc = 0; rloc < 2; rloc++) {
        int row = wave * 2 + rloc;
        int grow = h0 + row;
        f32x4 acc[4] = {{0,0,0,0},{0,0,0,0},{0,0,0,0},{0,0,0,0}};
#pragma unroll
        for (int ks = 0; ks < 5; ks++) {
            int tap = 2 * ks + (q >> 1); if (tap > 8) tap = 8;
            int dh = tap / 3 - 1, dw = tap % 3 - 1;
            int half = q & 1;
            int lr = row + 1 + dh;
#pragma unroll
            for (int t = 0; t < 4; t++) {
                int c = 1 + dw + t * 16 + n;
                cv.u = h1s[(lr * 66 + c) * 2 + (half ^ ((c >> 2) & 1))];
                MF(acc[t], ah[ks], cv.v);
                MF(acc[t], al[ks], cv.v);
            }
        }
        float sv[4][4];
#pragma unroll
        for (int t = 0; t < 4; t++)
#pragma unroll
            for (int r = 0; r < 4; r++)
                sv[t][r] = silu(acc[t][r] + b2q[r]);
#pragma unroll
        for (int r = 0; r < 4; r++) tt[r] += sv[0][r] + sv[1][r] + sv[2][r] + sv[3][r];
        if (grow == 0 || grow == HH - 1) {
            int off = (grow == 0) ? OFF_ROW0 : OFF_ROW1;
#pragma unroll
            for (int r = 0; r < 4; r++) {
                float x = sv[0][r] + sv[1][r] + sv[2][r] + sv[3][r];
#pragma unroll
                for (int d = 1; d < 16; d <<= 1) x += __shfl_xor(x, d, 64);
                if (n == 0) atomicAdd(&wsf[off + b * 16 + q * 4 + r], x);
            }
        }
        if (blockIdx.x == 0 && n == 0)
#pragma unroll
            for (int r = 0; r < 4; r++) cs0[r] += sv[0][r];
        if (blockIdx.x == 7 && n == 15)
#pragma unroll
            for (int r = 0; r < 4; r++) cs1[r] += sv[3][r];
        if ((grow == 0 || grow == HH - 1)) {
            int hi = (grow == 0) ? 0 : 1;
            if (blockIdx.x == 0 && n == 0)
#pragma unroll
                for (int r = 0; r < 4; r++)
                    wsf[OFF_COR + ((b * 2 + hi) * 2 + 0) * 16 + q * 4 + r] = sv[0][r];
            if (blockIdx.x == 7 && n == 15)
#pragma unroll
                for (int r = 0; r < 4; r++)
                    wsf[OFF_COR + ((b * 2 + hi) * 2 + 1) * 16 + q * 4 + r] = sv[3][r];
        }
    }
    if (blockIdx.x == 0 && n == 0)
#pragma unroll
        for (int r = 0; r < 4; r++) atomicAdd(&wsf[OFF_COL0 + b * 16 + q * 4 + r], cs0[r]);
    if (blockIdx.x == 7 && n == 15)
#pragma unroll
        for (int r = 0; r < 4; r++) atomicAdd(&wsf[OFF_COL1 + b * 16 + q * 4 + r], cs1[r]);
#pragma unroll
    for (int r = 0; r < 4; r++) {
        float x = tt[r];
#pragma unroll
        for (int d = 1; d < 16; d <<= 1) x += __shfl_xor(x, d, 64);
        tt[r] = x;
    }
    if (n == 0)
#pragma unroll
        for (int r = 0; r < 4; r++) part[wave][q * 4 + r] = tt[r];
    __syncthreads();
    if (tx < 16)
        atomicAdd(&wsf[OFF_TOT + b * 16 + tx],
                  part[0][tx] + part[1][tx] + part[2][tx] + part[3][tx]);
}

// ---------------- filter: mean via edge algebra, taps, and band-matrix A-fragments ----------------
__global__ void filter_kernel(const float* __restrict__ w3, const float* __restrict__ b3,
                              float* __restrict__ wsf) {
    int b = blockIdx.x, t = threadIdx.x;   // 160 threads
    __shared__ float red[160];
    float val = 0.f;
    if (t < 144) {
        int ic = t / 9, tap = t % 9, kh = tap / 3, kw = tap % 3;
        float T = wsf[OFF_TOT + b * 16 + ic];
        int hi = -1, wi = -1;
        if (kh == 0) { T -= wsf[OFF_ROW1 + b * 16 + ic]; hi = 1; }
        else if (kh == 2) { T -= wsf[OFF_ROW0 + b * 16 + ic]; hi = 0; }
        if (kw == 0) { T -= wsf[OFF_COL1 + b * 16 + ic]; wi = 1; }
        else if (kw == 2) { T -= wsf[OFF_COL0 + b * 16 + ic]; wi = 0; }
        if (hi >= 0 && wi >= 0) T += wsf[OFF_COR + ((b * 2 + hi) * 2 + wi) * 16 + ic];
        val = w3[t] * T;
    }
    red[t] = val;
    __syncthreads();
    __shared__ float sh_mean;
    if (t == 0) {
        float S = 0.f;
        for (int i = 0; i < 144; i++) S += red[i];
        sh_mean = b3[0] + S * (1.f / (float)PIX);
    }
    __syncthreads();
    float scale = fminf(2.5f, fmaxf(-2.5f, sh_mean));
    float sd = exp2f(scale);
    float fs = ceilf(3.f * sd + 0.5f);
    float e = 0.f, c = 0.f;
    if (t < 37) {
        float x = (float)(t - 18);
        if (fabsf(x) <= fs) {
            float qq = x / sd;
            e = __expf(-0.5f * qq * qq);
            c = -x / (sd * sd * sd * 6.28318530717958647692f) * e;
        }
    }
    __shared__ float sa[40], sb2[40];
    if (t < 37) { sa[t] = e; sb2[t] = fabsf(c); }
    __syncthreads();
    __shared__ float Se, Sc;
    if (t == 0) {
        float a = 0.f, d = 0.f;
        for (int i = 0; i < 37; i++) { a += sa[i]; d += sb2[i]; }
        Se = a; Sc = d;
    }
    __syncthreads();
    __shared__ float sEn[37], sCn[37];
    if (t < 37) { sEn[t] = e / Se; sCn[t] = c / Sc; }
    __syncthreads();
    if (t < 64) {
        int r = t & 15, q = t >> 4;
        uint4* afr = (uint4*)(wsf + OFF_AFR) + (size_t)b * 640 + t;
#pragma unroll
        for (int ks = 0; ks < 2; ks++) {
            unsigned short eh[8], em[8], el[8], chp[8], cmp[8];
#pragma unroll
            for (int j2 = 0; j2 < 8; j2++) {
                int d = ks * 32 + q * 8 + j2 - r;
                bool ok = (d >= 0) && (d <= 36);
                float ve = ok ? sEn[ok ? d : 0] : 0.f;
                float vc = ok ? sCn[ok ? d : 0] : 0.f;
                eh[j2] = bfbits(ve);
                float r1 = ve - ubf(eh[j2]);
                em[j2] = bfbits(r1);
                el[j2] = bfbits(r1 - ubf(em[j2]));
                chp[j2] = bfbits(vc);
                cmp[j2] = bfbits(vc - ubf(chp[j2]));
            }
#define PK2(a0, a1) ((unsigned)(a0) | ((unsigned)(a1) << 16))
            afr[(ks * 3 + 0) * 64] = make_uint4(PK2(eh[0], eh[1]), PK2(eh[2], eh[3]), PK2(eh[4], eh[5]), PK2(eh[6], eh[7]));
            afr[(ks * 3 + 1) * 64] = make_uint4(PK2(em[0], em[1]), PK2(em[2], em[3]), PK2(em[4], em[5]), PK2(em[6], em[7]));
            afr[(ks * 3 + 2) * 64] = make_uint4(PK2(el[0], el[1]), PK2(el[2], el[3]), PK2(el[4], el[5]), PK2(el[6], el[7]));
            afr[(6 + ks * 2 + 0) * 64] = make_uint4(PK2(chp[0], chp[1]), PK2(chp[2], chp[3]), PK2(chp[4], chp[5]), PK2(chp[6], chp[7]));
            afr[(6 + ks * 2 + 1) * 64] = make_uint4(PK2(cmp[0], cmp[1]), PK2(cmp[2], cmp[3]), PK2(cmp[4], cmp[5]), PK2(cmp[6], cmp[7]));
#undef PK2
        }
    }
}

// ---------------- horizontal pass (MFMA): batch -> xg -> t0..t3, tpl transposed [j][h] ----------------
// Round-9: batch-issued staging (T14). All 30 global loads hoisted into registers with
// ONE waitcnt, then converts+LDS writes. Removes ~10x serial HBM round-trips per block.
__global__ __launch_bounds__(256) void horiz_kernel(const float* __restrict__ batch,
                                                    const float* __restrict__ gcm,
                                                    const float* __restrict__ wsf,
                                                    unsigned short* __restrict__ tp0,
                                                    float* __restrict__ tp1,
                                                    float* __restrict__ tp2,
                                                    unsigned short* __restrict__ tp3) {
    __shared__ unsigned short sx[7 * 32 * 84];   // 37,632 B
    int tx = threadIdx.x;
    int lane = tx & 63, wave = tx >> 6;
    int n = lane & 15, q = lane >> 4;
    int j0 = blockIdx.x * 32, h0 = blockIdx.y * 32, b = blockIdx.z;
    const float* pb = batch + (size_t)(b * 3) * PIX;
    float g0 = gcm[0], g1 = gcm[1], g2 = gcm[2];
    float g3 = gcm[3], g4 = gcm[4], g5 = gcm[5];
    float g6 = gcm[6], g7 = gcm[7], g8 = gcm[8];
    // phase 1: issue ALL staging loads (10 rounds x 3 ch) into registers
    float v0r[10], v1r[10], v2r[10];
#pragma unroll
    for (int it = 0; it < 10; it++) {
        int i = tx + it * 256;                       // 0..2559
        int hh = i / 80, sc = i - hh * 80;
        int gc = j0 - 18 + sc;
        float v0 = 0.f, v1 = 0.f, v2 = 0.f;
        if ((unsigned)gc < (unsigned)WW) {
            size_t p = (size_t)(h0 + hh) * WW + gc;
            v0 = pb[p]; v1 = pb[(size_t)PIX + p]; v2 = pb[2 * (size_t)PIX + p];
        }
        v0r[it] = v0; v1r[it] = v1; v2r[it] = v2;
    }
    // phase 2: convert + LDS write
#pragma unroll
    for (int it = 0; it < 10; it++) {
        int i = tx + it * 256;
        int hh = i / 80, sc = i - hh * 80;
        float v0 = v0r[it], v1 = v1r[it], v2 = v2r[it];
        float x0 = g0 * v0 + g1 * v1 + g2 * v2;
        float x1 = g3 * v0 + g4 * v1 + g5 * v2;
        float x2 = g6 * v0 + g7 * v1 + g8 * v2;
        int o = hh * 84 + sc;
        sx[o] = bfbits(x0);
        unsigned short h1 = bfbits(x1); sx[2688 + o] = h1;
        float r1 = x1 - ubf(h1); unsigned short m1 = bfbits(r1); sx[2 * 2688 + o] = m1;
        sx[3 * 2688 + o] = bfbits(r1 - ubf(m1));
        unsigned short h2 = bfbits(x2); sx[4 * 2688 + o] = h2;
        float r2 = x2 - ubf(h2); unsigned short m2 = bfbits(r2); sx[5 * 2688 + o] = m2;
        sx[6 * 2688 + o] = bfbits(r2 - ubf(m2));
    }
    const uint4* afr = (const uint4*)(wsf + OFF_AFR) + (size_t)b * 640 + lane;
    union { uint4 u; bf16x8 v; } cv;
    bf16x8 Ae[2][3], Ac[2][2];
#pragma unroll
    for (int ks = 0; ks < 2; ks++) {
#pragma unroll
        for (int p = 0; p < 3; p++) { cv.u = afr[(ks * 3 + p) * 64]; Ae[ks][p] = cv.v; }
#pragma unroll
        for (int p = 0; p < 2; p++) { cv.u = afr[(6 + ks * 2 + p) * 64]; Ac[ks][p] = cv.v; }
    }
    __syncthreads();
    int jt = wave & 1, ht = wave >> 1;
    f32x4 a0 = {0,0,0,0}, a1 = {0,0,0,0}, a2 = {0,0,0,0}, a3 = {0,0,0,0};
    int rb = (ht * 16 + n) * 84 + jt * 16 + q * 8;
#pragma unroll
    for (int ks = 0; ks < 2; ks++) {
        int rk = rb + ks * 32;
        bf16x8 B0  = ldb(sx, rk);
        bf16x8 B1h = ldb(sx, 2688 + rk), B1m = ldb(sx, 2 * 2688 + rk), B1l = ldb(sx, 3 * 2688 + rk);
        bf16x8 B2h = ldb(sx, 4 * 2688 + rk), B2m = ldb(sx, 5 * 2688 + rk), B2l = ldb(sx, 6 * 2688 + rk);
        MF(a0, Ae[ks][0], B0); MF(a0, Ae[ks][1], B0);
        MF(a3, Ac[ks][0], B0); MF(a3, Ac[ks][1], B0);
        MF(a1, Ae[ks][0], B1h); MF(a1, Ae[ks][0], B1m); MF(a1, Ae[ks][1], B1h);
        MF(a1, Ae[ks][0], B1l); MF(a1, Ae[ks][2], B1h); MF(a1, Ae[ks][1], B1m);
        MF(a2, Ae[ks][0], B2h); MF(a2, Ae[ks][0], B2m); MF(a2, Ae[ks][1], B2h);
        MF(a2, Ae[ks][0], B2l); MF(a2, Ae[ks][2], B2h); MF(a2, Ae[ks][1], B2m);
    }
    int jo = j0 + jt * 16 + q * 4;
    int ho = h0 + ht * 16 + n;
#pragma unroll
    for (int r = 0; r < 4; r++) {
        size_t ix = ((size_t)b * 512 + (jo + r)) * 512 + ho;
        tp0[ix] = bfbits(a0[r]);
        tp1[ix] = a1[r];
        tp2[ix] = a2[r];
        tp3[ix] = bfbits(a3[r]);
    }
}

// ---------------- vertical pass (MFMA) + final math -> out ch0,1,5 ----------------
// Round-9: batch-issued staging (T14), same pattern as horiz.
__global__ __launch_bounds__(256) void vert_kernel(const float* __restrict__ wsf,
                                                   const unsigned short* __restrict__ tp0,
                                                   const float* __restrict__ tp1,
                                                   const float* __restrict__ tp2,
                                                   const unsigned short* __restrict__ tp3,
                                                   float* __restrict__ out) {
    __shared__ unsigned short sb[8 * 32 * 84];   // 43,008 B
    int tx = threadIdx.x;
    int lane = tx & 63, wave = tx >> 6;
    int n = lane & 15, q = lane >> 4;
    int j0 = blockIdx.x * 32, r0 = blockIdx.y * 32, b = blockIdx.z;
    // phase 1: issue ALL staging loads into registers
    unsigned short w0r[10], w7r[10];
    float f1r[10], f2r[10];
#pragma unroll
    for (int it = 0; it < 10; it++) {
        int i = tx + it * 256;
        int jj = i / 80, sr = i - jj * 80;
        int gh = r0 - 18 + sr;
        unsigned short w0 = 0, w7 = 0; float f1 = 0.f, f2 = 0.f;
        if ((unsigned)gh < (unsigned)HH) {
            size_t ix = ((size_t)b * 512 + (j0 + jj)) * 512 + gh;
            w0 = tp0[ix]; f1 = tp1[ix]; f2 = tp2[ix]; w7 = tp3[ix];
        }
        w0r[it] = w0; f1r[it] = f1; f2r[it] = f2; w7r[it] = w7;
    }
    // phase 2: convert + LDS write
#pragma unroll
    for (int it = 0; it < 10; it++) {
        int i = tx + it * 256;
        int jj = i / 80, sr = i - jj * 80;
        int o = jj * 84 + sr;
        float f1 = f1r[it], f2 = f2r[it];
        sb[o] = w0r[it];
        unsigned short h1 = bfbits(f1); sb[2688 + o] = h1;
        float r1 = f1 - ubf(h1); unsigned short m1 = bfbits(r1); sb[2 * 2688 + o] = m1;
        sb[3 * 2688 + o] = bfbits(r1 - ubf(m1));
        unsigned short h2 = bfbits(f2); sb[4 * 2688 + o] = h2;
        float r2 = f2 - ubf(h2); unsigned short m2 = bfbits(r2); sb[5 * 2688 + o] = m2;
        sb[6 * 2688 + o] = bfbits(r2 - ubf(m2));
        sb[7 * 2688 + o] = w7r[it];
    }
    const uint4* afr = (const uint4*)(wsf + OFF_AFR) + (size_t)b * 640 + lane;
    union { uint4 u; bf16x8 v; } cv;
    bf16x8 Ae[2][3], Ac[2][2];
#pragma unroll
    for (int ks = 0; ks < 2; ks++) {
#pragma unroll
        for (int p = 0; p < 3; p++) { cv.u = afr[(ks * 3 + p) * 64]; Ae[ks][p] = cv.v; }
#pragma unroll
        for (int p = 0; p < 2; p++) { cv.u = afr[(6 + ks * 2 + p) * 64]; Ac[ks][p] = cv.v; }
    }
    __syncthreads();
    int ct = wave & 1, rt = wave >> 1;
    f32x4 aE = {0,0,0,0}, aX = {0,0,0,0}, aY = {0,0,0,0}, aL = {0,0,0,0}, aLL = {0,0,0,0};
    int rb = (ct * 16 + n) * 84 + rt * 16 + q * 8;
#pragma unroll
    for (int ks = 0; ks < 2; ks++) {
        int rk = rb + ks * 32;
        bf16x8 B0  = ldb(sb, rk);
        bf16x8 B1h = ldb(sb, 2688 + rk), B1m = ldb(sb, 2 * 2688 + rk), B1l = ldb(sb, 3 * 2688 + rk);
        bf16x8 B2h = ldb(sb, 4 * 2688 + rk), B2m = ldb(sb, 5 * 2688 + rk), B2l = ldb(sb, 6 * 2688 + rk);
        bf16x8 B3  = ldb(sb, 7 * 2688 + rk);
        MF(aE, Ae[ks][0], B0); MF(aE, Ae[ks][1], B0);
        MF(aX, Ac[ks][0], B0); MF(aX, Ac[ks][1], B0);
        MF(aY, Ae[ks][0], B3); MF(aY, Ae[ks][1], B3);
        MF(aL, Ae[ks][0], B1h); MF(aL, Ae[ks][0], B1m); MF(aL, Ae[ks][1], B1h);
        MF(aL, Ae[ks][0], B1l); MF(aL, Ae[ks][2], B1h); MF(aL, Ae[ks][1], B1m);
        MF(aLL, Ae[ks][0], B2h); MF(aLL, Ae[ks][0], B2m); MF(aLL, Ae[ks][1], B2h);
        MF(aLL, Ae[ks][0], B2l); MF(aLL, Ae[ks][2], B2h); MF(aLL, Ae[ks][1], B2m);
    }
    int ho = r0 + rt * 16 + q * 4;
    int jo = j0 + ct * 16 + n;
#pragma unroll
    for (int r = 0; r < 4; r++) {
        float E = aE[r], Ex = aX[r], Ey = aY[r], El = aL[r], Ell = aLL[r];
        float Hf = atanf(El / (Ell + EPSF));
        float S = logf((El * El + Ell * Ell) / (E * E + EPSF) + EPSF);
        float rx = Ex / (E + EPSF), ry = Ey / (E + EPSF);
        float Wv = atanf(rx * rx + ry * ry);
        size_t base = (size_t)(b * 6) * PIX + (size_t)(ho + r) * WW + jo;
        out[base] = Hf;
        out[base + PIX] = S;
        out[base + 5 * (size_t)PIX] = Wv;
    }
}

extern "C" void kernel_launch(void* const* d_in, const int* in_sizes, int n_in,
                              void* d_out, int out_size, void* d_ws, size_t ws_size,
                              hipStream_t stream) {
    const float* batch = (const float*)d_in[0];
    const float* gcm   = (const float*)d_in[1];
    const float* w1    = (const float*)d_in[2];
    const float* b1    = (const float*)d_in[3];
    const float* w2    = (const float*)d_in[4];
    const float* b2    = (const float*)d_in[5];
    const float* w3    = (const float*)d_in[6];
    const float* b3    = (const float*)d_in[7];
    float* out = (float*)d_out;

    if (ws_size < WS_NEEDED) return;

    float* wsf = (float*)d_ws;
    unsigned short* tp0 = (unsigned short*)((char*)d_ws + OFF_TP0);
    float* tp1 = (float*)((char*)d_ws + OFF_TP1);
    float* tp2 = (float*)((char*)d_ws + OFF_TP2);
    unsigned short* tp3 = (unsigned short*)((char*)d_ws + OFF_TP3);

    prep_kernel<<<dim3(1), dim3(256), 0, stream>>>(w1, w2, wsf);
    conv12_kernel<<<dim3(8, 64, 8), dim3(256), 0, stream>>>(
        batch, (const unsigned short*)(wsf + OFF_W1R), b1,
        (const unsigned short*)(wsf + OFF_WR), b2, wsf, out);
    filter_kernel<<<dim3(8), dim3(160), 0, stream>>>(w3, b3, wsf);
    horiz_kernel<<<dim3(16, 16, 8), dim3(256), 0, stream>>>(batch, gcm, wsf, tp0, tp1, tp2, tp3);
    vert_kernel<<<dim3(16, 16, 8), dim3(256), 0, stream>>>(wsf, tp0, tp1, tp2, tp3, out);
}